// Round 1
// baseline (527.504 us; speedup 1.0000x reference)
//
#include <hip/hip_runtime.h>

// ---------------------------------------------------------------------------
// TransformerBlock: LN1 -> QK proj + low-rank V -> reversed-causal attention
// (scale 1/sqrt(D)=1/32) -> residual -> LN2 -> GELU FFN -> residual.
// B=2 S=2048 D=1024 H=16 HD=64 R=32 F=4096. All d_in/d_out fp32; internal
// compute bf16 MFMA (threshold is ~2% of max|ref|).
// Workspace layout (needs ~90 MB):
//   0        WqT   [1024x1024] bf16 (row n=h*64+e, col d)
//   2M       WkT   [1024x1024] bf16
//   4M       WvdT  [512x1024]  bf16 (row n=h*32+r)
//   5M       WvuB  [H,R,HD]    bf16 (flat convert)
//   5.25M    W1T   [4096x1024] bf16
//   13.25M   W2T   [1024x4096] bf16
//   21.25M   hbuf  [4096x1024] bf16 (LN1 out, later LN2 out)
//   29.25M   qall  [4096x1024] bf16   } ubuf [4096x4096] bf16 reuses
//   37.25M   kall  [4096x1024] bf16   } 29.25..61.25M after attention
//   45.25M   vdall [4096x512]  bf16   } is consumed
//   49.25M   vT    [B,H,HD,S]  bf16   }
//   57.25M   ob    [4096x1024] f32 (attention out; dead after LN2)
//   73.25M   x2    [4096x1024] f32 (residual after attention)
// ---------------------------------------------------------------------------

typedef unsigned short u16;
typedef __attribute__((ext_vector_type(4))) float f32x4;
typedef __attribute__((ext_vector_type(8))) __bf16 bf16x8;

#define B_ 2
#define S_ 2048
#define D_ 1024
#define H_ 16
#define HD_ 64
#define R_ 32
#define F_ 4096
#define M_ (B_ * S_)  // 4096 rows

__device__ __forceinline__ u16 f2bf(float f) {
  union { float f; unsigned u; } v; v.f = f;
  unsigned u = v.u;
  return (u16)((u + 0x7FFFu + ((u >> 16) & 1u)) >> 16);  // RNE
}
__device__ __forceinline__ float bf2f(u16 h) {
  union { unsigned u; float f; } v; v.u = ((unsigned)h) << 16;
  return v.f;
}

typedef __attribute__((address_space(1))) void gvoid;
typedef __attribute__((address_space(3))) void lvoid;
// async global->LDS, 16B/lane; lds base must be wave-uniform (lane*16 implicit)
__device__ __forceinline__ void gload_lds16(const void* g, void* l) {
  __builtin_amdgcn_global_load_lds((gvoid*)(void*)g, (lvoid*)l, 16, 0, 0);
}

__device__ __forceinline__ float gelu_f(float x) {
  float t = tanhf(0.7978845608028654f * (x + 0.044715f * x * x * x));
  return 0.5f * x * (1.0f + t);
}

// ---- fp32 [Rr,Cc] (batched) -> bf16 transposed [Cc,Rr] --------------------
__global__ __launch_bounds__(256) void wtrans(const float* __restrict__ in,
                                              u16* __restrict__ out,
                                              int Rr, int Cc, long ibs, long obs) {
  __shared__ float tile[32][33];
  const float* ip = in + (size_t)blockIdx.z * ibs;
  u16* op = out + (size_t)blockIdx.z * obs;
  int c0 = blockIdx.x * 32, r0 = blockIdx.y * 32;
  int tx = threadIdx.x & 31, ty = threadIdx.x >> 5;  // 32 x 8
#pragma unroll
  for (int j = 0; j < 32; j += 8)
    tile[ty + j][tx] = ip[(size_t)(r0 + ty + j) * Cc + c0 + tx];
  __syncthreads();
#pragma unroll
  for (int j = 0; j < 32; j += 8)
    op[(size_t)(c0 + ty + j) * Rr + r0 + tx] = f2bf(tile[tx][ty + j]);
}

// ---- flat fp32 -> bf16 -----------------------------------------------------
__global__ __launch_bounds__(256) void wconv(const float* __restrict__ in,
                                             u16* __restrict__ out, int n) {
  int i = (blockIdx.x * 256 + threadIdx.x) * 4;
  if (i < n) {
    float4 v = *(const float4*)&in[i];
    ushort4 o;
    o.x = f2bf(v.x); o.y = f2bf(v.y); o.z = f2bf(v.z); o.w = f2bf(v.w);
    *(ushort4*)&out[i] = o;
  }
}

// ---- LayerNorm (optionally fused residual add + x2 passthrough) -----------
// one block per row of D=1024; 256 threads x float4
__global__ __launch_bounds__(256) void ln_kernel(const float* __restrict__ xin,
                                                 const float* __restrict__ addin,
                                                 const float* __restrict__ gam,
                                                 const float* __restrict__ bet,
                                                 u16* __restrict__ hout,
                                                 float* __restrict__ x2out) {
  int row = blockIdx.x, tid = threadIdx.x;
  size_t base = (size_t)row * D_ + tid * 4;
  float4 v = *(const float4*)&xin[base];
  if (addin) {
    float4 a = *(const float4*)&addin[base];
    v.x += a.x; v.y += a.y; v.z += a.z; v.w += a.w;
  }
  if (x2out) *(float4*)&x2out[base] = v;
  float s = v.x + v.y + v.z + v.w;
  float ss = v.x * v.x + v.y * v.y + v.z * v.z + v.w * v.w;
#pragma unroll
  for (int off = 32; off > 0; off >>= 1) {
    s += __shfl_down(s, off);
    ss += __shfl_down(ss, off);
  }
  __shared__ float red[8];
  int wv = tid >> 6;
  if ((tid & 63) == 0) { red[wv] = s; red[4 + wv] = ss; }
  __syncthreads();
  if (tid == 0) {
    float s1 = red[0] + red[1] + red[2] + red[3];
    float s2 = red[4] + red[5] + red[6] + red[7];
    float mu = s1 * (1.0f / D_);
    red[0] = mu;
    red[1] = s2 * (1.0f / D_) - mu * mu;
  }
  __syncthreads();
  float mu = red[0];
  float rstd = rsqrtf(red[1] + 1e-5f);
  int ci = tid * 4;
  ushort4 o;
  o.x = f2bf((v.x - mu) * rstd * gam[ci + 0] + bet[ci + 0]);
  o.y = f2bf((v.y - mu) * rstd * gam[ci + 1] + bet[ci + 1]);
  o.z = f2bf((v.z - mu) * rstd * gam[ci + 2] + bet[ci + 2]);
  o.w = f2bf((v.w - mu) * rstd * gam[ci + 3] + bet[ci + 3]);
  *(ushort4*)&hout[base] = o;
}

// ---- NT GEMM: C[m,n] = sum_k A[m,k]*Bt[n,k] (+bias, +gelu, +res) ----------
// m97 structure: 128x128 tile, BK=32, 4 waves (2x2 of 64x64), 16x16x32 MFMA,
// global_load_lds width-16 staging, 2 barriers / K-step.
// MODE 0: bf16 out + bias; 1: bf16 out + bias + gelu; 2: f32 out + bias + res
template <int MODE>
__global__ __launch_bounds__(256) void gemm_nt(const u16* __restrict__ A,
                                               const u16* __restrict__ Bt,
                                               int K, int lda, int ldb,
                                               const float* __restrict__ bias,
                                               const float* __restrict__ res,
                                               void* __restrict__ Cout, int ldc) {
  __shared__ u16 As[128 * 32];
  __shared__ u16 Bs[128 * 32];
  int tid = threadIdx.x;
  int lane = tid & 63, wid = tid >> 6;
  int wm = wid >> 1, wn = wid & 1;
  int row0 = blockIdx.y * 128, col0 = blockIdx.x * 128;
  int l15 = lane & 15, g = lane >> 4;
  int srow = lane >> 2, scol = (lane & 3) * 8;  // staging: 4 lanes/row, 8 elems each
  f32x4 acc[4][4] = {};
  const u16* Ap = A + (size_t)row0 * lda;
  const u16* Bp = Bt + (size_t)col0 * ldb;
  for (int k0 = 0; k0 < K; k0 += 32) {
    __syncthreads();  // previous iter's frag reads done before overwrite
#pragma unroll
    for (int i = 0; i < 2; ++i) {
      int c = wid * 2 + i;  // chunk = 16 rows x 32 cols = 1KB, one wave-load
      gload_lds16(Ap + (size_t)(c * 16 + srow) * lda + k0 + scol, &As[c * 512]);
      gload_lds16(Bp + (size_t)(c * 16 + srow) * ldb + k0 + scol, &Bs[c * 512]);
    }
    __syncthreads();  // compiler drains vmcnt(0) before barrier
    bf16x8 af[4], bfr[4];
#pragma unroll
    for (int t = 0; t < 4; ++t) {
      af[t] = *(const bf16x8*)&As[(wm * 64 + t * 16 + l15) * 32 + g * 8];
      bfr[t] = *(const bf16x8*)&Bs[(wn * 64 + t * 16 + l15) * 32 + g * 8];
    }
#pragma unroll
    for (int mt = 0; mt < 4; ++mt)
#pragma unroll
      for (int nt = 0; nt < 4; ++nt)
        acc[mt][nt] = __builtin_amdgcn_mfma_f32_16x16x32_bf16(af[mt], bfr[nt],
                                                              acc[mt][nt], 0, 0, 0);
  }
  // epilogue: C/D layout col=lane&15, row=(lane>>4)*4+j  [verified m89/m91]
#pragma unroll
  for (int mt = 0; mt < 4; ++mt) {
#pragma unroll
    for (int nt = 0; nt < 4; ++nt) {
      int cc = col0 + wn * 64 + nt * 16 + l15;
      float bv = bias ? bias[cc] : 0.0f;
#pragma unroll
      for (int j = 0; j < 4; ++j) {
        int rr = row0 + wm * 64 + mt * 16 + g * 4 + j;
        float v = acc[mt][nt][j] + bv;
        if (MODE == 1) v = gelu_f(v);
        if (MODE == 2) {
          ((float*)Cout)[(size_t)rr * ldc + cc] = v + res[(size_t)rr * ldc + cc];
        } else {
          ((u16*)Cout)[(size_t)rr * ldc + cc] = f2bf(v);
        }
      }
    }
  }
}

// ---- low-rank V up-proj: v[t,h,e] = vd[t,h*32+r]·Wvu[h,r,e] + bvu; write Vᵀ
// block = (t-tile 64, h, b); writes v_t[(b,h),e][t] bf16 (coalesced via LDS)
__global__ __launch_bounds__(256) void vu_kernel(const u16* __restrict__ vd,
                                                 const u16* __restrict__ wvu,
                                                 const float* __restrict__ bvu,
                                                 u16* __restrict__ v_t) {
  int t0 = blockIdx.x * 64, h = blockIdx.y, b = blockIdx.z;
  __shared__ u16 vds[64][32];
  __shared__ u16 vt[64][65];
  int tid = threadIdx.x;
  {
    int rr2 = tid >> 2, c8 = (tid & 3) * 8;
    *(bf16x8*)&vds[rr2][c8] =
        *(const bf16x8*)&vd[(size_t)(b * S_ + t0 + rr2) * (H_ * R_) + h * R_ + c8];
  }
  __syncthreads();
  int e = tid & 63, tg = (tid >> 6) * 16;
  float wcol[32];
#pragma unroll
  for (int r = 0; r < 32; ++r) wcol[r] = bf2f(wvu[((size_t)h * R_ + r) * HD_ + e]);
  float bb = bvu[h * HD_ + e];
  for (int i = 0; i < 16; ++i) {
    int t = tg + i;
    float acc = bb;
#pragma unroll
    for (int r = 0; r < 32; ++r) acc += bf2f(vds[t][r]) * wcol[r];
    vt[t][e] = f2bf(acc);
  }
  __syncthreads();
  for (int idx = tid; idx < 64 * 64; idx += 256) {
    int e2 = idx >> 6, t2 = idx & 63;
    v_t[((size_t)(b * H_ + h) * HD_ + e2) * S_ + t0 + t2] = vt[t2][e2];
  }
}

// ---- attention: reversed-causal (key t >= query s), scale 1/32 ------------
// grid (S/64, H, B), 4 waves; wave w owns 16 queries s0 = bx*64+w*16.
// QK^T via MFMA (K-dim = HD, A=q rows, B=k^T); online softmax in D-frag
// layout (4 rows/lane); P relayout via per-wave LDS; PV against v_t.
__global__ __launch_bounds__(256) void attn_kernel(const u16* __restrict__ q,
                                                   const u16* __restrict__ k,
                                                   const u16* __restrict__ v_t,
                                                   float* __restrict__ o) {
  int lane = threadIdx.x & 63, w = threadIdx.x >> 6;
  int h = blockIdx.y, b = blockIdx.z;
  int s0 = blockIdx.x * 64 + w * 16;
  int r = lane & 15, g = lane >> 4;
  const u16* qp = q + (size_t)(b * S_) * D_ + h * HD_;
  const u16* kp = k + (size_t)(b * S_) * D_ + h * HD_;
  const u16* vp = v_t + (size_t)(b * H_ + h) * HD_ * S_;
  __shared__ u16 P[4][16 * 32];
  u16* Pw = P[w];
  bf16x8 aq0 = *(const bf16x8*)(qp + (size_t)(s0 + r) * D_ + g * 8);
  bf16x8 aq1 = *(const bf16x8*)(qp + (size_t)(s0 + r) * D_ + 32 + g * 8);
  f32x4 oa[4] = {};
  float m_[4], l_[4];
#pragma unroll
  for (int j = 0; j < 4; ++j) { m_[j] = -1e30f; l_[j] = 0.0f; }
  for (int kt = s0 & ~31; kt < S_; kt += 32) {
    f32x4 sc0 = {0.f, 0.f, 0.f, 0.f}, sc1 = {0.f, 0.f, 0.f, 0.f};
    {
      const u16* kr0 = kp + (size_t)(kt + r) * D_ + g * 8;
      sc0 = __builtin_amdgcn_mfma_f32_16x16x32_bf16(aq0, *(const bf16x8*)kr0, sc0, 0, 0, 0);
      sc0 = __builtin_amdgcn_mfma_f32_16x16x32_bf16(aq1, *(const bf16x8*)(kr0 + 32), sc0, 0, 0, 0);
      const u16* kr1 = kp + (size_t)(kt + 16 + r) * D_ + g * 8;
      sc1 = __builtin_amdgcn_mfma_f32_16x16x32_bf16(aq0, *(const bf16x8*)kr1, sc1, 0, 0, 0);
      sc1 = __builtin_amdgcn_mfma_f32_16x16x32_bf16(aq1, *(const bf16x8*)(kr1 + 32), sc1, 0, 0, 0);
    }
#pragma unroll
    for (int j = 0; j < 4; ++j) {
      int rowq = s0 + g * 4 + j;
      float p0 = (kt + r < rowq) ? -1e30f : sc0[j] * 0.03125f;
      float p1 = (kt + 16 + r < rowq) ? -1e30f : sc1[j] * 0.03125f;
      float mx = fmaxf(p0, p1);
#pragma unroll
      for (int off = 8; off > 0; off >>= 1) mx = fmaxf(mx, __shfl_xor(mx, off));
      float mn = fmaxf(m_[j], mx);
      float scale = __expf(m_[j] - mn);
      p0 = __expf(p0 - mn);
      p1 = __expf(p1 - mn);
      float sm = p0 + p1;
#pragma unroll
      for (int off = 8; off > 0; off >>= 1) sm += __shfl_xor(sm, off);
      l_[j] = l_[j] * scale + sm;
      m_[j] = mn;
      oa[0][j] *= scale; oa[1][j] *= scale; oa[2][j] *= scale; oa[3][j] *= scale;
      Pw[(g * 4 + j) * 32 + r] = f2bf(p0);
      Pw[(g * 4 + j) * 32 + 16 + r] = f2bf(p1);
    }
    asm volatile("s_waitcnt lgkmcnt(0)" ::: "memory");  // P writes visible in-wave
    bf16x8 pa = *(const bf16x8*)&Pw[r * 32 + g * 8];
#pragma unroll
    for (int et = 0; et < 4; ++et) {
      bf16x8 bv = *(const bf16x8*)(vp + (size_t)(et * 16 + r) * S_ + kt + g * 8);
      oa[et] = __builtin_amdgcn_mfma_f32_16x16x32_bf16(pa, bv, oa[et], 0, 0, 0);
    }
  }
#pragma unroll
  for (int j = 0; j < 4; ++j) {
    float inv = 1.0f / l_[j];
    size_t rbase = (size_t)(b * S_ + s0 + g * 4 + j) * D_ + h * HD_;
#pragma unroll
    for (int et = 0; et < 4; ++et) o[rbase + et * 16 + r] = oa[et][j] * inv;
  }
}

extern "C" void kernel_launch(void* const* d_in, const int* in_sizes, int n_in,
                              void* d_out, int out_size, void* d_ws, size_t ws_size,
                              hipStream_t stream) {
  const float* x = (const float*)d_in[0];
  const float* ln1_g = (const float*)d_in[1];
  const float* ln1_b = (const float*)d_in[2];
  const float* Wq = (const float*)d_in[3];
  const float* bq = (const float*)d_in[4];
  const float* Wk = (const float*)d_in[5];
  const float* bk = (const float*)d_in[6];
  const float* Wvd = (const float*)d_in[7];
  const float* bvd = (const float*)d_in[8];
  const float* Wvu = (const float*)d_in[9];
  const float* bvu = (const float*)d_in[10];
  const float* ln2_g = (const float*)d_in[11];
  const float* ln2_b = (const float*)d_in[12];
  const float* W1 = (const float*)d_in[13];
  const float* b1 = (const float*)d_in[14];
  const float* W2 = (const float*)d_in[15];
  const float* b2 = (const float*)d_in[16];
  float* out = (float*)d_out;
  (void)in_sizes; (void)n_in; (void)out_size; (void)ws_size;

  char* ws = (char*)d_ws;
  const size_t MB = 1024 * 1024;
  u16* wqT = (u16*)(ws + 0);
  u16* wkT = (u16*)(ws + 2 * MB);
  u16* wvdT = (u16*)(ws + 4 * MB);
  u16* wvuB = (u16*)(ws + 5 * MB);
  u16* w1T = (u16*)(ws + 5 * MB + 256 * 1024);
  u16* w2T = (u16*)(ws + 13 * MB + 256 * 1024);
  u16* hbuf = (u16*)(ws + 21 * MB + 256 * 1024);
  u16* qall = (u16*)(ws + 29 * MB + 256 * 1024);
  u16* kall = (u16*)(ws + 37 * MB + 256 * 1024);
  u16* vdall = (u16*)(ws + 45 * MB + 256 * 1024);
  u16* vT = (u16*)(ws + 49 * MB + 256 * 1024);
  float* ob = (float*)(ws + 57 * MB + 256 * 1024);
  float* x2 = (float*)(ws + 73 * MB + 256 * 1024);
  u16* ubuf = qall;  // 32MB reuse of q/k/vd/vT(+4MB of ob), all dead by FFN1

  dim3 blk(256);
  // weight convert/transpose (every call; fold into GEMM staging later)
  wtrans<<<dim3(2, 32, 16), blk, 0, stream>>>(Wq, wqT, 1024, 64, 65536L, 65536L);
  wtrans<<<dim3(2, 32, 16), blk, 0, stream>>>(Wk, wkT, 1024, 64, 65536L, 65536L);
  wtrans<<<dim3(1, 32, 16), blk, 0, stream>>>(Wvd, wvdT, 1024, 32, 32768L, 32768L);
  wconv<<<dim3(32), blk, 0, stream>>>(Wvu, wvuB, H_ * R_ * HD_);
  wtrans<<<dim3(128, 32, 1), blk, 0, stream>>>(W1, w1T, 1024, 4096, 0L, 0L);
  wtrans<<<dim3(32, 128, 1), blk, 0, stream>>>(W2, w2T, 4096, 1024, 0L, 0L);
  // LN1
  ln_kernel<<<dim3(M_), blk, 0, stream>>>(x, (const float*)nullptr, ln1_g, ln1_b,
                                          hbuf, (float*)nullptr);
  // projections: q/k [4096,1024], vd [4096,512]
  gemm_nt<0><<<dim3(8, 32), blk, 0, stream>>>(hbuf, wqT, 1024, 1024, 1024, bq,
                                              (const float*)nullptr, (void*)qall, 1024);
  gemm_nt<0><<<dim3(8, 32), blk, 0, stream>>>(hbuf, wkT, 1024, 1024, 1024, bk,
                                              (const float*)nullptr, (void*)kall, 1024);
  gemm_nt<0><<<dim3(4, 32), blk, 0, stream>>>(hbuf, wvdT, 1024, 1024, 1024, bvd,
                                              (const float*)nullptr, (void*)vdall, 512);
  vu_kernel<<<dim3(S_ / 64, H_, B_), blk, 0, stream>>>(vdall, wvuB, bvu, vT);
  attn_kernel<<<dim3(S_ / 64, H_, B_), blk, 0, stream>>>(qall, kall, vT, ob);
  // LN2 with fused residual (x2 = x + attn_out)
  ln_kernel<<<dim3(M_), blk, 0, stream>>>(x, ob, ln2_g, ln2_b, hbuf, x2);
  // FFN
  gemm_nt<1><<<dim3(32, 32), blk, 0, stream>>>(hbuf, w1T, 1024, 1024, 1024, b1,
                                               (const float*)nullptr, (void*)ubuf, 4096);
  gemm_nt<2><<<dim3(8, 32), blk, 0, stream>>>(ubuf, w2T, 4096, 4096, 4096, b2, x2,
                                              (void*)out, 1024);
}

// Round 3
// 382.149 us; speedup vs baseline: 1.3804x; 1.3804x over previous
//
#include <hip/hip_runtime.h>

// ---------------------------------------------------------------------------
// TransformerBlock: LN1 -> QK proj + low-rank V -> reversed-causal attention
// (scale 1/sqrt(D)=1/32) -> residual -> LN2 -> GELU FFN -> residual.
// B=2 S=2048 D=1024 H=16 HD=64 R=32 F=4096. All d_in/d_out fp32; internal
// compute bf16 MFMA.
// R2 fix: attention staging was writing only 8 of 16 rows per wave slice
// (1024B per gload_lds16 vs 2048B needed) -> NaN from uninitialized LDS.
// Now two gload_lds16 per tile per wave (rows srow, srow+8).
// ---------------------------------------------------------------------------

typedef unsigned short u16;
typedef __attribute__((ext_vector_type(4))) float f32x4;
typedef __attribute__((ext_vector_type(8))) __bf16 bf16x8;

#define B_ 2
#define S_ 2048
#define D_ 1024
#define H_ 16
#define HD_ 64
#define R_ 32
#define F_ 4096
#define M_ (B_ * S_)  // 4096 rows

__device__ __forceinline__ u16 f2bf(float f) {
  union { float f; unsigned u; } v; v.f = f;
  unsigned u = v.u;
  return (u16)((u + 0x7FFFu + ((u >> 16) & 1u)) >> 16);  // RNE
}
__device__ __forceinline__ float bf2f(u16 h) {
  union { unsigned u; float f; } v; v.u = ((unsigned)h) << 16;
  return v.f;
}

typedef __attribute__((address_space(1))) void gvoid;
typedef __attribute__((address_space(3))) void lvoid;
// async global->LDS, 16B/lane; lds base must be wave-uniform (lane*16 implicit)
__device__ __forceinline__ void gload_lds16(const void* g, void* l) {
  __builtin_amdgcn_global_load_lds((gvoid*)(void*)g, (lvoid*)l, 16, 0, 0);
}

__device__ __forceinline__ float gelu_f(float x) {
  float t = tanhf(0.7978845608028654f * (x + 0.044715f * x * x * x));
  return 0.5f * x * (1.0f + t);
}

// ---- fp32 [Rr,Cc] (batched) -> bf16 transposed [Cc,Rr] --------------------
__global__ __launch_bounds__(256) void wtrans(const float* __restrict__ in,
                                              u16* __restrict__ out,
                                              int Rr, int Cc, long ibs, long obs) {
  __shared__ float tile[32][33];
  const float* ip = in + (size_t)blockIdx.z * ibs;
  u16* op = out + (size_t)blockIdx.z * obs;
  int c0 = blockIdx.x * 32, r0 = blockIdx.y * 32;
  int tx = threadIdx.x & 31, ty = threadIdx.x >> 5;  // 32 x 8
#pragma unroll
  for (int j = 0; j < 32; j += 8)
    tile[ty + j][tx] = ip[(size_t)(r0 + ty + j) * Cc + c0 + tx];
  __syncthreads();
#pragma unroll
  for (int j = 0; j < 32; j += 8)
    op[(size_t)(c0 + ty + j) * Rr + r0 + tx] = f2bf(tile[tx][ty + j]);
}

// ---- flat fp32 -> bf16 -----------------------------------------------------
__global__ __launch_bounds__(256) void wconv(const float* __restrict__ in,
                                             u16* __restrict__ out, int n) {
  int i = (blockIdx.x * 256 + threadIdx.x) * 4;
  if (i < n) {
    float4 v = *(const float4*)&in[i];
    ushort4 o;
    o.x = f2bf(v.x); o.y = f2bf(v.y); o.z = f2bf(v.z); o.w = f2bf(v.w);
    *(ushort4*)&out[i] = o;
  }
}

// ---- LayerNorm (optionally fused residual add + x2 passthrough) -----------
__global__ __launch_bounds__(256) void ln_kernel(const float* __restrict__ xin,
                                                 const float* __restrict__ addin,
                                                 const float* __restrict__ gam,
                                                 const float* __restrict__ bet,
                                                 u16* __restrict__ hout,
                                                 float* __restrict__ x2out) {
  int row = blockIdx.x, tid = threadIdx.x;
  size_t base = (size_t)row * D_ + tid * 4;
  float4 v = *(const float4*)&xin[base];
  if (addin) {
    float4 a = *(const float4*)&addin[base];
    v.x += a.x; v.y += a.y; v.z += a.z; v.w += a.w;
  }
  if (x2out) *(float4*)&x2out[base] = v;
  float s = v.x + v.y + v.z + v.w;
  float ss = v.x * v.x + v.y * v.y + v.z * v.z + v.w * v.w;
#pragma unroll
  for (int off = 32; off > 0; off >>= 1) {
    s += __shfl_down(s, off);
    ss += __shfl_down(ss, off);
  }
  __shared__ float red[8];
  int wv = tid >> 6;
  if ((tid & 63) == 0) { red[wv] = s; red[4 + wv] = ss; }
  __syncthreads();
  if (tid == 0) {
    float s1 = red[0] + red[1] + red[2] + red[3];
    float s2 = red[4] + red[5] + red[6] + red[7];
    float mu = s1 * (1.0f / D_);
    red[0] = mu;
    red[1] = s2 * (1.0f / D_) - mu * mu;
  }
  __syncthreads();
  float mu = red[0];
  float rstd = rsqrtf(red[1] + 1e-5f);
  int ci = tid * 4;
  ushort4 o;
  o.x = f2bf((v.x - mu) * rstd * gam[ci + 0] + bet[ci + 0]);
  o.y = f2bf((v.y - mu) * rstd * gam[ci + 1] + bet[ci + 1]);
  o.z = f2bf((v.z - mu) * rstd * gam[ci + 2] + bet[ci + 2]);
  o.w = f2bf((v.w - mu) * rstd * gam[ci + 3] + bet[ci + 3]);
  *(ushort4*)&hout[base] = o;
}

// ---- NT GEMM: C[m,n] = sum_k A[m,k]*Bt[n,k] (+bias, +gelu, +res) ----------
// m97 structure: 128x128 tile, BK=32, 4 waves, 16x16x32 MFMA.
template <int MODE>
__global__ __launch_bounds__(256) void gemm_nt(const u16* __restrict__ A,
                                               const u16* __restrict__ Bt,
                                               int K, int lda, int ldb,
                                               const float* __restrict__ bias,
                                               const float* __restrict__ res,
                                               void* __restrict__ Cout, int ldc) {
  __shared__ u16 As[128 * 32];
  __shared__ u16 Bs[128 * 32];
  int tid = threadIdx.x;
  int lane = tid & 63, wid = tid >> 6;
  int wm = wid >> 1, wn = wid & 1;
  int row0 = blockIdx.y * 128, col0 = blockIdx.x * 128;
  int l15 = lane & 15, g = lane >> 4;
  int srow = lane >> 2, scol = (lane & 3) * 8;
  f32x4 acc[4][4] = {};
  const u16* Ap = A + (size_t)row0 * lda;
  const u16* Bp = Bt + (size_t)col0 * ldb;
  for (int k0 = 0; k0 < K; k0 += 32) {
    __syncthreads();
#pragma unroll
    for (int i = 0; i < 2; ++i) {
      int c = wid * 2 + i;
      gload_lds16(Ap + (size_t)(c * 16 + srow) * lda + k0 + scol, &As[c * 512]);
      gload_lds16(Bp + (size_t)(c * 16 + srow) * ldb + k0 + scol, &Bs[c * 512]);
    }
    __syncthreads();
    bf16x8 af[4], bfr[4];
#pragma unroll
    for (int t = 0; t < 4; ++t) {
      af[t] = *(const bf16x8*)&As[(wm * 64 + t * 16 + l15) * 32 + g * 8];
      bfr[t] = *(const bf16x8*)&Bs[(wn * 64 + t * 16 + l15) * 32 + g * 8];
    }
#pragma unroll
    for (int mt = 0; mt < 4; ++mt)
#pragma unroll
      for (int nt = 0; nt < 4; ++nt)
        acc[mt][nt] = __builtin_amdgcn_mfma_f32_16x16x32_bf16(af[mt], bfr[nt],
                                                              acc[mt][nt], 0, 0, 0);
  }
#pragma unroll
  for (int mt = 0; mt < 4; ++mt) {
#pragma unroll
    for (int nt = 0; nt < 4; ++nt) {
      int cc = col0 + wn * 64 + nt * 16 + l15;
      float bv = bias ? bias[cc] : 0.0f;
#pragma unroll
      for (int j = 0; j < 4; ++j) {
        int rr = row0 + wm * 64 + mt * 16 + g * 4 + j;
        float v = acc[mt][nt][j] + bv;
        if (MODE == 1) v = gelu_f(v);
        if (MODE == 2) {
          ((float*)Cout)[(size_t)rr * ldc + cc] = v + res[(size_t)rr * ldc + cc];
        } else {
          ((u16*)Cout)[(size_t)rr * ldc + cc] = f2bf(v);
        }
      }
    }
  }
}

// ---- low-rank V up-proj -> V^T [b,h][e][t] bf16 ----------------------------
__global__ __launch_bounds__(256) void vu_kernel(const u16* __restrict__ vd,
                                                 const u16* __restrict__ wvu,
                                                 const float* __restrict__ bvu,
                                                 u16* __restrict__ v_t) {
  int t0 = blockIdx.x * 64, h = blockIdx.y, b = blockIdx.z;
  __shared__ u16 vds[64][32];
  __shared__ u16 vt[64][65];
  int tid = threadIdx.x;
  {
    int rr2 = tid >> 2, c8 = (tid & 3) * 8;
    *(bf16x8*)&vds[rr2][c8] =
        *(const bf16x8*)&vd[(size_t)(b * S_ + t0 + rr2) * (H_ * R_) + h * R_ + c8];
  }
  __syncthreads();
  int e = tid & 63, tg = (tid >> 6) * 16;
  float wcol[32];
#pragma unroll
  for (int r = 0; r < 32; ++r) wcol[r] = bf2f(wvu[((size_t)h * R_ + r) * HD_ + e]);
  float bb = bvu[h * HD_ + e];
  for (int i = 0; i < 16; ++i) {
    int t = tg + i;
    float acc = bb;
#pragma unroll
    for (int r = 0; r < 32; ++r) acc += bf2f(vds[t][r]) * wcol[r];
    vt[t][e] = f2bf(acc);
  }
  __syncthreads();
  for (int idx = tid; idx < 64 * 64; idx += 256) {
    int e2 = idx >> 6, t2 = idx & 63;
    v_t[((size_t)(b * H_ + h) * HD_ + e2) * S_ + t0 + t2] = vt[t2][e2];
  }
}

// ---- attention v2: reversed-causal (key t >= query s), scale 1/32 ---------
// grid (S/64, H, B), 4 waves; wave w owns 16 queries s0 = qb + w*16.
// Swapped QK^T: ST = mfma(K, Q^T) -> rows=keys, cols=queries => per-lane
// softmax state (4 shuffles/step). O^T = mfma(V^T, P^T). K/V^T tiles staged
// block-wide in LDS via global_load_lds with pre-swizzled source
// (byte ^= (row&7)<<4); same XOR on all LDS reads (involution both sides).
__global__ __launch_bounds__(256) void attn_kernel(const u16* __restrict__ q,
                                                   const u16* __restrict__ k,
                                                   const u16* __restrict__ v_t,
                                                   float* __restrict__ o) {
  int tid = threadIdx.x;
  int lane = tid & 63, w = tid >> 6;
  int h = blockIdx.y, b = blockIdx.z;
  int qb = blockIdx.x * 64;
  int s0 = qb + w * 16;
  int r = lane & 15, g = lane >> 4;
  const u16* qp = q + (size_t)(b * S_) * D_ + h * HD_;
  const u16* kp = k + (size_t)(b * S_) * D_ + h * HD_;
  const u16* vp = v_t + (size_t)(b * H_ + h) * HD_ * S_;

  __shared__ u16 Ks[64 * 64];     // [key][d], rows swizzled
  __shared__ u16 Vs[64 * 64];     // [e][key], rows swizzled
  __shared__ u16 Pl[4][16 * 64];  // per-wave P^T [q][key], swizzled
  u16* Pw = Pl[w];

  // Q B-frags: col q = r, d = db*32 + g*8 (contiguous row reads)
  bf16x8 aq0 = *(const bf16x8*)(qp + (size_t)(s0 + r) * D_ + g * 8);
  bf16x8 aq1 = *(const bf16x8*)(qp + (size_t)(s0 + r) * D_ + 32 + g * 8);

  f32x4 oa[4] = {};              // O^T: row e = et*16 + g*4+j, col q = r
  float m_ = -1e30f, l_ = 0.0f;  // per-lane (query r) online softmax state

  // staging: wave w owns rows w*16..w*16+15 (16 rows x 128B = 2 wave-loads,
  // rows srow and srow+8; (srow+8)&7 == srow&7 so the swizzle is identical)
  int srow = w * 16 + (lane >> 3);
  int ssw = ((lane & 7) * 16) ^ (((lane >> 3) & 7) << 4);  // pre-swz byte in row

  int xr = (r & 7) << 4;                // read-side XOR (row = ..*16 + r)
  int kq0 = ((g * 16) ^ xr) >> 1;       // elem offset, k-group 0
  int kq1 = ((64 + g * 16) ^ xr) >> 1;  // elem offset, k-group 1
  int qrow = s0 + r;

  for (int kt = qb; kt < S_; kt += 64) {
    __syncthreads();  // previous step's LDS reads done
    gload_lds16((const char*)(kp + (size_t)(kt + srow) * D_) + ssw, &Ks[w * 1024]);
    gload_lds16((const char*)(kp + (size_t)(kt + srow + 8) * D_) + ssw,
                &Ks[w * 1024 + 512]);
    gload_lds16((const char*)(vp + (size_t)srow * S_ + kt) + ssw, &Vs[w * 1024]);
    gload_lds16((const char*)(vp + (size_t)(srow + 8) * S_ + kt) + ssw,
                &Vs[w * 1024 + 512]);
    __syncthreads();  // drains vmcnt(0): tiles ready

    // QK^T: sc[blk] rows = keys blk*16 + g*4+j, col = query r
    f32x4 sc[4] = {};
#pragma unroll
    for (int blk = 0; blk < 4; ++blk) {
      bf16x8 a0 = *(const bf16x8*)&Ks[((blk * 16 + r) << 6) + kq0];
      bf16x8 a1 = *(const bf16x8*)&Ks[((blk * 16 + r) << 6) + kq1];
      sc[blk] = __builtin_amdgcn_mfma_f32_16x16x32_bf16(a0, aq0, sc[blk], 0, 0, 0);
      sc[blk] = __builtin_amdgcn_mfma_f32_16x16x32_bf16(a1, aq1, sc[blk], 0, 0, 0);
    }

    // mask + online softmax (per-lane, 4 shuffles total)
    float p[16];
    float mx = -1e30f;
#pragma unroll
    for (int blk = 0; blk < 4; ++blk)
#pragma unroll
      for (int j = 0; j < 4; ++j) {
        int kk = kt + blk * 16 + g * 4 + j;
        float v = (kk < qrow) ? -1e30f : sc[blk][j] * 0.03125f;
        p[blk * 4 + j] = v;
        mx = fmaxf(mx, v);
      }
    mx = fmaxf(mx, __shfl_xor(mx, 16));
    mx = fmaxf(mx, __shfl_xor(mx, 32));
    float mn = fmaxf(m_, mx);
    float scl = __expf(m_ - mn);
    m_ = mn;
    float sm = 0.0f;
#pragma unroll
    for (int i = 0; i < 16; ++i) {
      p[i] = __expf(p[i] - mn);
      sm += p[i];
    }
    sm += __shfl_xor(sm, 16);
    sm += __shfl_xor(sm, 32);
    l_ = l_ * scl + sm;
#pragma unroll
    for (int et = 0; et < 4; ++et) oa[et] *= scl;

    // P -> per-wave LDS (bf16, swizzled), then read back as PV B-frags
#pragma unroll
    for (int blk = 0; blk < 4; ++blk) {
      uint2 pk;
      pk.x = (unsigned)f2bf(p[blk * 4 + 0]) | ((unsigned)f2bf(p[blk * 4 + 1]) << 16);
      pk.y = (unsigned)f2bf(p[blk * 4 + 2]) | ((unsigned)f2bf(p[blk * 4 + 3]) << 16);
      *(uint2*)&Pw[(r << 6) + ((((blk << 5) + (g << 3)) ^ xr) >> 1)] = pk;
    }
    asm volatile("s_waitcnt lgkmcnt(0)" ::: "memory");  // P writes visible in-wave
    bf16x8 pb0 = *(const bf16x8*)&Pw[(r << 6) + kq0];
    bf16x8 pb1 = *(const bf16x8*)&Pw[(r << 6) + kq1];
#pragma unroll
    for (int et = 0; et < 4; ++et) {
      bf16x8 v0 = *(const bf16x8*)&Vs[((et * 16 + r) << 6) + kq0];
      bf16x8 v1 = *(const bf16x8*)&Vs[((et * 16 + r) << 6) + kq1];
      oa[et] = __builtin_amdgcn_mfma_f32_16x16x32_bf16(v0, pb0, oa[et], 0, 0, 0);
      oa[et] = __builtin_amdgcn_mfma_f32_16x16x32_bf16(v1, pb1, oa[et], 0, 0, 0);
    }
  }

  float inv = 1.0f / l_;
#pragma unroll
  for (int et = 0; et < 4; ++et)
#pragma unroll
    for (int j = 0; j < 4; ++j)
      o[(size_t)(b * S_ + s0 + r) * D_ + h * HD_ + et * 16 + g * 4 + j] =
          oa[et][j] * inv;
}

extern "C" void kernel_launch(void* const* d_in, const int* in_sizes, int n_in,
                              void* d_out, int out_size, void* d_ws, size_t ws_size,
                              hipStream_t stream) {
  const float* x = (const float*)d_in[0];
  const float* ln1_g = (const float*)d_in[1];
  const float* ln1_b = (const float*)d_in[2];
  const float* Wq = (const float*)d_in[3];
  const float* bq = (const float*)d_in[4];
  const float* Wk = (const float*)d_in[5];
  const float* bk = (const float*)d_in[6];
  const float* Wvd = (const float*)d_in[7];
  const float* bvd = (const float*)d_in[8];
  const float* Wvu = (const float*)d_in[9];
  const float* bvu = (const float*)d_in[10];
  const float* ln2_g = (const float*)d_in[11];
  const float* ln2_b = (const float*)d_in[12];
  const float* W1 = (const float*)d_in[13];
  const float* b1 = (const float*)d_in[14];
  const float* W2 = (const float*)d_in[15];
  const float* b2 = (const float*)d_in[16];
  float* out = (float*)d_out;
  (void)in_sizes; (void)n_in; (void)out_size; (void)ws_size;

  char* ws = (char*)d_ws;
  const size_t MB = 1024 * 1024;
  u16* wqT = (u16*)(ws + 0);
  u16* wkT = (u16*)(ws + 2 * MB);
  u16* wvdT = (u16*)(ws + 4 * MB);
  u16* wvuB = (u16*)(ws + 5 * MB);
  u16* w1T = (u16*)(ws + 5 * MB + 256 * 1024);
  u16* w2T = (u16*)(ws + 13 * MB + 256 * 1024);
  u16* hbuf = (u16*)(ws + 21 * MB + 256 * 1024);
  u16* qall = (u16*)(ws + 29 * MB + 256 * 1024);
  u16* kall = (u16*)(ws + 37 * MB + 256 * 1024);
  u16* vdall = (u16*)(ws + 45 * MB + 256 * 1024);
  u16* vT = (u16*)(ws + 49 * MB + 256 * 1024);
  float* ob = (float*)(ws + 57 * MB + 256 * 1024);
  float* x2 = (float*)(ws + 73 * MB + 256 * 1024);
  u16* ubuf = qall;

  dim3 blk(256);
  wtrans<<<dim3(2, 32, 16), blk, 0, stream>>>(Wq, wqT, 1024, 64, 65536L, 65536L);
  wtrans<<<dim3(2, 32, 16), blk, 0, stream>>>(Wk, wkT, 1024, 64, 65536L, 65536L);
  wtrans<<<dim3(1, 32, 16), blk, 0, stream>>>(Wvd, wvdT, 1024, 32, 32768L, 32768L);
  wconv<<<dim3(32), blk, 0, stream>>>(Wvu, wvuB, H_ * R_ * HD_);
  wtrans<<<dim3(128, 32, 1), blk, 0, stream>>>(W1, w1T, 1024, 4096, 0L, 0L);
  wtrans<<<dim3(32, 128, 1), blk, 0, stream>>>(W2, w2T, 4096, 1024, 0L, 0L);
  ln_kernel<<<dim3(M_), blk, 0, stream>>>(x, (const float*)nullptr, ln1_g, ln1_b,
                                          hbuf, (float*)nullptr);
  gemm_nt<0><<<dim3(8, 32), blk, 0, stream>>>(hbuf, wqT, 1024, 1024, 1024, bq,
                                              (const float*)nullptr, (void*)qall, 1024);
  gemm_nt<0><<<dim3(8, 32), blk, 0, stream>>>(hbuf, wkT, 1024, 1024, 1024, bk,
                                              (const float*)nullptr, (void*)kall, 1024);
  gemm_nt<0><<<dim3(4, 32), blk, 0, stream>>>(hbuf, wvdT, 1024, 1024, 1024, bvd,
                                              (const float*)nullptr, (void*)vdall, 512);
  vu_kernel<<<dim3(S_ / 64, H_, B_), blk, 0, stream>>>(vdall, wvuB, bvu, vT);
  attn_kernel<<<dim3(S_ / 64, H_, B_), blk, 0, stream>>>(qall, kall, vT, ob);
  ln_kernel<<<dim3(M_), blk, 0, stream>>>(x, ob, ln2_g, ln2_b, hbuf, x2);
  gemm_nt<1><<<dim3(32, 32), blk, 0, stream>>>(hbuf, w1T, 1024, 1024, 1024, b1,
                                               (const float*)nullptr, (void*)ubuf, 4096);
  gemm_nt<2><<<dim3(8, 32), blk, 0, stream>>>(ubuf, w2T, 4096, 4096, 4096, b2, x2,
                                              (void*)out, 1024);
}

// Round 4
// 328.861 us; speedup vs baseline: 1.6040x; 1.1620x over previous
//
#include <hip/hip_runtime.h>

// ---------------------------------------------------------------------------
// TransformerBlock: LN1 -> QK proj + low-rank V -> reversed-causal attention
// (scale 1/sqrt(D)=1/32) -> residual -> LN2 -> GELU FFN -> residual.
// B=2 S=2048 D=1024 H=16 HD=64 R=32 F=4096. All d_in/d_out fp32; internal
// compute bf16 MFMA.
// R3: gemm_nt -> 2-phase double-buffered LDS (T3-minimum): STAGE(next) issued
// before COMPUTE(cur), one barrier per K-step, statically-named ping-pong
// buffers (K unrolled x2) so ds_reads provably don't alias the in-flight
// global_load_lds writes. Targets the 1-block/CU GEMMs (FFN2/QK) where
// cross-block wave overlap can't hide stage latency.
// ---------------------------------------------------------------------------

typedef unsigned short u16;
typedef __attribute__((ext_vector_type(4))) float f32x4;
typedef __attribute__((ext_vector_type(8))) __bf16 bf16x8;

#define B_ 2
#define S_ 2048
#define D_ 1024
#define H_ 16
#define HD_ 64
#define R_ 32
#define F_ 4096
#define M_ (B_ * S_)  // 4096 rows

__device__ __forceinline__ u16 f2bf(float f) {
  union { float f; unsigned u; } v; v.f = f;
  unsigned u = v.u;
  return (u16)((u + 0x7FFFu + ((u >> 16) & 1u)) >> 16);  // RNE
}
__device__ __forceinline__ float bf2f(u16 h) {
  union { unsigned u; float f; } v; v.u = ((unsigned)h) << 16;
  return v.f;
}

typedef __attribute__((address_space(1))) void gvoid;
typedef __attribute__((address_space(3))) void lvoid;
// async global->LDS, 16B/lane; lds base must be wave-uniform (lane*16 implicit)
__device__ __forceinline__ void gload_lds16(const void* g, void* l) {
  __builtin_amdgcn_global_load_lds((gvoid*)(void*)g, (lvoid*)l, 16, 0, 0);
}

__device__ __forceinline__ float gelu_f(float x) {
  float t = tanhf(0.7978845608028654f * (x + 0.044715f * x * x * x));
  return 0.5f * x * (1.0f + t);
}

// ---- fp32 [Rr,Cc] (batched) -> bf16 transposed [Cc,Rr] --------------------
__global__ __launch_bounds__(256) void wtrans(const float* __restrict__ in,
                                              u16* __restrict__ out,
                                              int Rr, int Cc, long ibs, long obs) {
  __shared__ float tile[32][33];
  const float* ip = in + (size_t)blockIdx.z * ibs;
  u16* op = out + (size_t)blockIdx.z * obs;
  int c0 = blockIdx.x * 32, r0 = blockIdx.y * 32;
  int tx = threadIdx.x & 31, ty = threadIdx.x >> 5;  // 32 x 8
#pragma unroll
  for (int j = 0; j < 32; j += 8)
    tile[ty + j][tx] = ip[(size_t)(r0 + ty + j) * Cc + c0 + tx];
  __syncthreads();
#pragma unroll
  for (int j = 0; j < 32; j += 8)
    op[(size_t)(c0 + ty + j) * Rr + r0 + tx] = f2bf(tile[tx][ty + j]);
}

// ---- flat fp32 -> bf16 -----------------------------------------------------
__global__ __launch_bounds__(256) void wconv(const float* __restrict__ in,
                                             u16* __restrict__ out, int n) {
  int i = (blockIdx.x * 256 + threadIdx.x) * 4;
  if (i < n) {
    float4 v = *(const float4*)&in[i];
    ushort4 o;
    o.x = f2bf(v.x); o.y = f2bf(v.y); o.z = f2bf(v.z); o.w = f2bf(v.w);
    *(ushort4*)&out[i] = o;
  }
}

// ---- LayerNorm (optionally fused residual add + x2 passthrough) -----------
__global__ __launch_bounds__(256) void ln_kernel(const float* __restrict__ xin,
                                                 const float* __restrict__ addin,
                                                 const float* __restrict__ gam,
                                                 const float* __restrict__ bet,
                                                 u16* __restrict__ hout,
                                                 float* __restrict__ x2out) {
  int row = blockIdx.x, tid = threadIdx.x;
  size_t base = (size_t)row * D_ + tid * 4;
  float4 v = *(const float4*)&xin[base];
  if (addin) {
    float4 a = *(const float4*)&addin[base];
    v.x += a.x; v.y += a.y; v.z += a.z; v.w += a.w;
  }
  if (x2out) *(float4*)&x2out[base] = v;
  float s = v.x + v.y + v.z + v.w;
  float ss = v.x * v.x + v.y * v.y + v.z * v.z + v.w * v.w;
#pragma unroll
  for (int off = 32; off > 0; off >>= 1) {
    s += __shfl_down(s, off);
    ss += __shfl_down(ss, off);
  }
  __shared__ float red[8];
  int wv = tid >> 6;
  if ((tid & 63) == 0) { red[wv] = s; red[4 + wv] = ss; }
  __syncthreads();
  if (tid == 0) {
    float s1 = red[0] + red[1] + red[2] + red[3];
    float s2 = red[4] + red[5] + red[6] + red[7];
    float mu = s1 * (1.0f / D_);
    red[0] = mu;
    red[1] = s2 * (1.0f / D_) - mu * mu;
  }
  __syncthreads();
  float mu = red[0];
  float rstd = rsqrtf(red[1] + 1e-5f);
  int ci = tid * 4;
  ushort4 o;
  o.x = f2bf((v.x - mu) * rstd * gam[ci + 0] + bet[ci + 0]);
  o.y = f2bf((v.y - mu) * rstd * gam[ci + 1] + bet[ci + 1]);
  o.z = f2bf((v.z - mu) * rstd * gam[ci + 2] + bet[ci + 2]);
  o.w = f2bf((v.w - mu) * rstd * gam[ci + 3] + bet[ci + 3]);
  *(ushort4*)&hout[base] = o;
}

// ---- NT GEMM: C[m,n] = sum_k A[m,k]*Bt[n,k] (+bias, +gelu, +res) ----------
// 128x128 tile, BK=32, 4 waves (2x2 of 64x64), 16x16x32 MFMA.
// 2-phase dbuf: STAGE(next half) || COMPUTE(cur), 1 barrier/K-step.
// MODE 0: bf16 out + bias; 1: bf16 out + bias + gelu; 2: f32 out + bias + res
template <int MODE>
__global__ __launch_bounds__(256) void gemm_nt(const u16* __restrict__ A,
                                               const u16* __restrict__ Bt,
                                               int K, int lda, int ldb,
                                               const float* __restrict__ bias,
                                               const float* __restrict__ res,
                                               void* __restrict__ Cout, int ldc) {
  __shared__ __align__(16) u16 As0[128 * 32];
  __shared__ __align__(16) u16 Bs0[128 * 32];
  __shared__ __align__(16) u16 As1[128 * 32];
  __shared__ __align__(16) u16 Bs1[128 * 32];
  int tid = threadIdx.x;
  int lane = tid & 63, wid = tid >> 6;
  int wm = wid >> 1, wn = wid & 1;
  int row0 = blockIdx.y * 128, col0 = blockIdx.x * 128;
  int l15 = lane & 15, g = lane >> 4;
  int srow = lane >> 2, scol = (lane & 3) * 8;
  f32x4 acc[4][4] = {};
  const u16* Ap = A + (size_t)row0 * lda;
  const u16* Bp = Bt + (size_t)col0 * ldb;

  auto STAGE = [&](u16* AS, u16* BS, int kk) {
#pragma unroll
    for (int i = 0; i < 2; ++i) {
      int c = wid * 2 + i;  // chunk = 16 rows x 32 cols = 1KB, one wave-load
      gload_lds16(Ap + (size_t)(c * 16 + srow) * lda + kk + scol, &AS[c * 512]);
      gload_lds16(Bp + (size_t)(c * 16 + srow) * ldb + kk + scol, &BS[c * 512]);
    }
  };
  auto COMPUTE = [&](const u16* AS, const u16* BS) {
    bf16x8 af[4], bfr[4];
#pragma unroll
    for (int t = 0; t < 4; ++t) {
      af[t] = *(const bf16x8*)&AS[(wm * 64 + t * 16 + l15) * 32 + g * 8];
      bfr[t] = *(const bf16x8*)&BS[(wn * 64 + t * 16 + l15) * 32 + g * 8];
    }
#pragma unroll
    for (int mt = 0; mt < 4; ++mt)
#pragma unroll
      for (int nt = 0; nt < 4; ++nt)
        acc[mt][nt] = __builtin_amdgcn_mfma_f32_16x16x32_bf16(af[mt], bfr[nt],
                                                              acc[mt][nt], 0, 0, 0);
  };

  STAGE(As0, Bs0, 0);
  __syncthreads();  // drains vmcnt(0): tile 0 ready
  for (int k0 = 0; k0 < K; k0 += 64) {  // K % 64 == 0 for all call sites
    if (k0 + 32 < K) STAGE(As1, Bs1, k0 + 32);
    COMPUTE(As0, Bs0);
    __syncthreads();  // reads of As0 retired + As1 staging drained
    if (k0 + 64 < K) STAGE(As0, Bs0, k0 + 64);
    COMPUTE(As1, Bs1);
    __syncthreads();
  }

  // epilogue: C/D layout col=lane&15, row=(lane>>4)*4+j  [verified m89/m91]
#pragma unroll
  for (int mt = 0; mt < 4; ++mt) {
#pragma unroll
    for (int nt = 0; nt < 4; ++nt) {
      int cc = col0 + wn * 64 + nt * 16 + l15;
      float bv = bias ? bias[cc] : 0.0f;
#pragma unroll
      for (int j = 0; j < 4; ++j) {
        int rr = row0 + wm * 64 + mt * 16 + g * 4 + j;
        float v = acc[mt][nt][j] + bv;
        if (MODE == 1) v = gelu_f(v);
        if (MODE == 2) {
          ((float*)Cout)[(size_t)rr * ldc + cc] = v + res[(size_t)rr * ldc + cc];
        } else {
          ((u16*)Cout)[(size_t)rr * ldc + cc] = f2bf(v);
        }
      }
    }
  }
}

// ---- low-rank V up-proj -> V^T [b,h][e][t] bf16 ----------------------------
__global__ __launch_bounds__(256) void vu_kernel(const u16* __restrict__ vd,
                                                 const u16* __restrict__ wvu,
                                                 const float* __restrict__ bvu,
                                                 u16* __restrict__ v_t) {
  int t0 = blockIdx.x * 64, h = blockIdx.y, b = blockIdx.z;
  __shared__ u16 vds[64][32];
  __shared__ u16 vt[64][65];
  int tid = threadIdx.x;
  {
    int rr2 = tid >> 2, c8 = (tid & 3) * 8;
    *(bf16x8*)&vds[rr2][c8] =
        *(const bf16x8*)&vd[(size_t)(b * S_ + t0 + rr2) * (H_ * R_) + h * R_ + c8];
  }
  __syncthreads();
  int e = tid & 63, tg = (tid >> 6) * 16;
  float wcol[32];
#pragma unroll
  for (int r = 0; r < 32; ++r) wcol[r] = bf2f(wvu[((size_t)h * R_ + r) * HD_ + e]);
  float bb = bvu[h * HD_ + e];
  for (int i = 0; i < 16; ++i) {
    int t = tg + i;
    float acc = bb;
#pragma unroll
    for (int r = 0; r < 32; ++r) acc += bf2f(vds[t][r]) * wcol[r];
    vt[t][e] = f2bf(acc);
  }
  __syncthreads();
  for (int idx = tid; idx < 64 * 64; idx += 256) {
    int e2 = idx >> 6, t2 = idx & 63;
    v_t[((size_t)(b * H_ + h) * HD_ + e2) * S_ + t0 + t2] = vt[t2][e2];
  }
}

// ---- attention: reversed-causal (key t >= query s), scale 1/32 ------------
// grid (S/64, H, B), 4 waves; wave w owns 16 queries s0 = qb + w*16.
// Swapped QK^T: ST = mfma(K, Q^T) -> rows=keys, cols=queries => per-lane
// softmax state (4 shuffles/step). O^T = mfma(V^T, P^T). K/V^T tiles staged
// block-wide in LDS via global_load_lds with pre-swizzled source
// (byte ^= (row&7)<<4); same XOR on all LDS reads (involution both sides).
__global__ __launch_bounds__(256) void attn_kernel(const u16* __restrict__ q,
                                                   const u16* __restrict__ k,
                                                   const u16* __restrict__ v_t,
                                                   float* __restrict__ o) {
  int tid = threadIdx.x;
  int lane = tid & 63, w = tid >> 6;
  int h = blockIdx.y, b = blockIdx.z;
  int qb = blockIdx.x * 64;
  int s0 = qb + w * 16;
  int r = lane & 15, g = lane >> 4;
  const u16* qp = q + (size_t)(b * S_) * D_ + h * HD_;
  const u16* kp = k + (size_t)(b * S_) * D_ + h * HD_;
  const u16* vp = v_t + (size_t)(b * H_ + h) * HD_ * S_;

  __shared__ u16 Ks[64 * 64];     // [key][d], rows swizzled
  __shared__ u16 Vs[64 * 64];     // [e][key], rows swizzled
  __shared__ u16 Pl[4][16 * 64];  // per-wave P^T [q][key], swizzled
  u16* Pw = Pl[w];

  // Q B-frags: col q = r, d = db*32 + g*8 (contiguous row reads)
  bf16x8 aq0 = *(const bf16x8*)(qp + (size_t)(s0 + r) * D_ + g * 8);
  bf16x8 aq1 = *(const bf16x8*)(qp + (size_t)(s0 + r) * D_ + 32 + g * 8);

  f32x4 oa[4] = {};              // O^T: row e = et*16 + g*4+j, col q = r
  float m_ = -1e30f, l_ = 0.0f;  // per-lane (query r) online softmax state

  // staging: wave w owns rows w*16..w*16+15 (16 rows x 128B = 2 wave-loads,
  // rows srow and srow+8; (srow+8)&7 == srow&7 so the swizzle is identical)
  int srow = w * 16 + (lane >> 3);
  int ssw = ((lane & 7) * 16) ^ (((lane >> 3) & 7) << 4);  // pre-swz byte in row

  int xr = (r & 7) << 4;                // read-side XOR (row = ..*16 + r)
  int kq0 = ((g * 16) ^ xr) >> 1;       // elem offset, k-group 0
  int kq1 = ((64 + g * 16) ^ xr) >> 1;  // elem offset, k-group 1
  int qrow = s0 + r;

  for (int kt = qb; kt < S_; kt += 64) {
    __syncthreads();  // previous step's LDS reads done
    gload_lds16((const char*)(kp + (size_t)(kt + srow) * D_) + ssw, &Ks[w * 1024]);
    gload_lds16((const char*)(kp + (size_t)(kt + srow + 8) * D_) + ssw,
                &Ks[w * 1024 + 512]);
    gload_lds16((const char*)(vp + (size_t)srow * S_ + kt) + ssw, &Vs[w * 1024]);
    gload_lds16((const char*)(vp + (size_t)(srow + 8) * S_ + kt) + ssw,
                &Vs[w * 1024 + 512]);
    __syncthreads();  // drains vmcnt(0): tiles ready

    // QK^T: sc[blk] rows = keys blk*16 + g*4+j, col = query r
    f32x4 sc[4] = {};
#pragma unroll
    for (int blk = 0; blk < 4; ++blk) {
      bf16x8 a0 = *(const bf16x8*)&Ks[((blk * 16 + r) << 6) + kq0];
      bf16x8 a1 = *(const bf16x8*)&Ks[((blk * 16 + r) << 6) + kq1];
      sc[blk] = __builtin_amdgcn_mfma_f32_16x16x32_bf16(a0, aq0, sc[blk], 0, 0, 0);
      sc[blk] = __builtin_amdgcn_mfma_f32_16x16x32_bf16(a1, aq1, sc[blk], 0, 0, 0);
    }

    // mask + online softmax (per-lane, 4 shuffles total)
    float p[16];
    float mx = -1e30f;
#pragma unroll
    for (int blk = 0; blk < 4; ++blk)
#pragma unroll
      for (int j = 0; j < 4; ++j) {
        int kk = kt + blk * 16 + g * 4 + j;
        float v = (kk < qrow) ? -1e30f : sc[blk][j] * 0.03125f;
        p[blk * 4 + j] = v;
        mx = fmaxf(mx, v);
      }
    mx = fmaxf(mx, __shfl_xor(mx, 16));
    mx = fmaxf(mx, __shfl_xor(mx, 32));
    float mn = fmaxf(m_, mx);
    float scl = __expf(m_ - mn);
    m_ = mn;
    float sm = 0.0f;
#pragma unroll
    for (int i = 0; i < 16; ++i) {
      p[i] = __expf(p[i] - mn);
      sm += p[i];
    }
    sm += __shfl_xor(sm, 16);
    sm += __shfl_xor(sm, 32);
    l_ = l_ * scl + sm;
#pragma unroll
    for (int et = 0; et < 4; ++et) oa[et] *= scl;

    // P -> per-wave LDS (bf16, swizzled), then read back as PV B-frags
#pragma unroll
    for (int blk = 0; blk < 4; ++blk) {
      uint2 pk;
      pk.x = (unsigned)f2bf(p[blk * 4 + 0]) | ((unsigned)f2bf(p[blk * 4 + 1]) << 16);
      pk.y = (unsigned)f2bf(p[blk * 4 + 2]) | ((unsigned)f2bf(p[blk * 4 + 3]) << 16);
      *(uint2*)&Pw[(r << 6) + ((((blk << 5) + (g << 3)) ^ xr) >> 1)] = pk;
    }
    asm volatile("s_waitcnt lgkmcnt(0)" ::: "memory");  // P writes visible in-wave
    bf16x8 pb0 = *(const bf16x8*)&Pw[(r << 6) + kq0];
    bf16x8 pb1 = *(const bf16x8*)&Pw[(r << 6) + kq1];
#pragma unroll
    for (int et = 0; et < 4; ++et) {
      bf16x8 v0 = *(const bf16x8*)&Vs[((et * 16 + r) << 6) + kq0];
      bf16x8 v1 = *(const bf16x8*)&Vs[((et * 16 + r) << 6) + kq1];
      oa[et] = __builtin_amdgcn_mfma_f32_16x16x32_bf16(v0, pb0, oa[et], 0, 0, 0);
      oa[et] = __builtin_amdgcn_mfma_f32_16x16x32_bf16(v1, pb1, oa[et], 0, 0, 0);
    }
  }

  float inv = 1.0f / l_;
#pragma unroll
  for (int et = 0; et < 4; ++et)
#pragma unroll
    for (int j = 0; j < 4; ++j)
      o[(size_t)(b * S_ + s0 + r) * D_ + h * HD_ + et * 16 + g * 4 + j] =
          oa[et][j] * inv;
}

extern "C" void kernel_launch(void* const* d_in, const int* in_sizes, int n_in,
                              void* d_out, int out_size, void* d_ws, size_t ws_size,
                              hipStream_t stream) {
  const float* x = (const float*)d_in[0];
  const float* ln1_g = (const float*)d_in[1];
  const float* ln1_b = (const float*)d_in[2];
  const float* Wq = (const float*)d_in[3];
  const float* bq = (const float*)d_in[4];
  const float* Wk = (const float*)d_in[5];
  const float* bk = (const float*)d_in[6];
  const float* Wvd = (const float*)d_in[7];
  const float* bvd = (const float*)d_in[8];
  const float* Wvu = (const float*)d_in[9];
  const float* bvu = (const float*)d_in[10];
  const float* ln2_g = (const float*)d_in[11];
  const float* ln2_b = (const float*)d_in[12];
  const float* W1 = (const float*)d_in[13];
  const float* b1 = (const float*)d_in[14];
  const float* W2 = (const float*)d_in[15];
  const float* b2 = (const float*)d_in[16];
  float* out = (float*)d_out;
  (void)in_sizes; (void)n_in; (void)out_size; (void)ws_size;

  char* ws = (char*)d_ws;
  const size_t MB = 1024 * 1024;
  u16* wqT = (u16*)(ws + 0);
  u16* wkT = (u16*)(ws + 2 * MB);
  u16* wvdT = (u16*)(ws + 4 * MB);
  u16* wvuB = (u16*)(ws + 5 * MB);
  u16* w1T = (u16*)(ws + 5 * MB + 256 * 1024);
  u16* w2T = (u16*)(ws + 13 * MB + 256 * 1024);
  u16* hbuf = (u16*)(ws + 21 * MB + 256 * 1024);
  u16* qall = (u16*)(ws + 29 * MB + 256 * 1024);
  u16* kall = (u16*)(ws + 37 * MB + 256 * 1024);
  u16* vdall = (u16*)(ws + 45 * MB + 256 * 1024);
  u16* vT = (u16*)(ws + 49 * MB + 256 * 1024);
  float* ob = (float*)(ws + 57 * MB + 256 * 1024);
  float* x2 = (float*)(ws + 73 * MB + 256 * 1024);
  u16* ubuf = qall;

  dim3 blk(256);
  wtrans<<<dim3(2, 32, 16), blk, 0, stream>>>(Wq, wqT, 1024, 64, 65536L, 65536L);
  wtrans<<<dim3(2, 32, 16), blk, 0, stream>>>(Wk, wkT, 1024, 64, 65536L, 65536L);
  wtrans<<<dim3(1, 32, 16), blk, 0, stream>>>(Wvd, wvdT, 1024, 32, 32768L, 32768L);
  wconv<<<dim3(32), blk, 0, stream>>>(Wvu, wvuB, H_ * R_ * HD_);
  wtrans<<<dim3(128, 32, 1), blk, 0, stream>>>(W1, w1T, 1024, 4096, 0L, 0L);
  wtrans<<<dim3(32, 128, 1), blk, 0, stream>>>(W2, w2T, 4096, 1024, 0L, 0L);
  ln_kernel<<<dim3(M_), blk, 0, stream>>>(x, (const float*)nullptr, ln1_g, ln1_b,
                                          hbuf, (float*)nullptr);
  gemm_nt<0><<<dim3(8, 32), blk, 0, stream>>>(hbuf, wqT, 1024, 1024, 1024, bq,
                                              (const float*)nullptr, (void*)qall, 1024);
  gemm_nt<0><<<dim3(8, 32), blk, 0, stream>>>(hbuf, wkT, 1024, 1024, 1024, bk,
                                              (const float*)nullptr, (void*)kall, 1024);
  gemm_nt<0><<<dim3(4, 32), blk, 0, stream>>>(hbuf, wvdT, 1024, 1024, 1024, bvd,
                                              (const float*)nullptr, (void*)vdall, 512);
  vu_kernel<<<dim3(S_ / 64, H_, B_), blk, 0, stream>>>(vdall, wvuB, bvu, vT);
  attn_kernel<<<dim3(S_ / 64, H_, B_), blk, 0, stream>>>(qall, kall, vT, ob);
  ln_kernel<<<dim3(M_), blk, 0, stream>>>(x, ob, ln2_g, ln2_b, hbuf, x2);
  gemm_nt<1><<<dim3(32, 32), blk, 0, stream>>>(hbuf, w1T, 1024, 1024, 1024, b1,
                                               (const float*)nullptr, (void*)ubuf, 4096);
  gemm_nt<2><<<dim3(8, 32), blk, 0, stream>>>(ubuf, w2T, 4096, 4096, 4096, b2, x2,
                                              (void*)out, 1024);
}

// Round 5
// 297.282 us; speedup vs baseline: 1.7744x; 1.1062x over previous
//
#include <hip/hip_runtime.h>

// ---------------------------------------------------------------------------
// TransformerBlock: LN1 -> QK proj + low-rank V -> reversed-causal attention
// (scale 1/sqrt(D)=1/32) -> residual -> LN2 -> GELU FFN -> residual.
// B=2 S=2048 D=1024 H=16 HD=64 R=32 F=4096. All d_in/d_out fp32; internal
// compute bf16 MFMA.
// R4: attention v3 —
//   * triangle pairing: block handles q-tiles bx*64 and S-64-bx*64 -> uniform
//     33 steps/block, 512 blocks (2/CU) flat occupancy
//   * double-buffered K/V staging (1 barrier/step, stage(next) || compute(cur))
//   * mask only on diagonal step; scale 1/32*log2e folded into WqT/bq;
//     exp2 instead of exp; P packed via v_cvt_pk_bf16_f32
// ---------------------------------------------------------------------------

typedef unsigned short u16;
typedef __attribute__((ext_vector_type(4))) float f32x4;
typedef __attribute__((ext_vector_type(8))) __bf16 bf16x8;

#define B_ 2
#define S_ 2048
#define D_ 1024
#define H_ 16
#define HD_ 64
#define R_ 32
#define F_ 4096
#define M_ (B_ * S_)  // 4096 rows
// (1/sqrt(D)) * log2(e): folded into Wq/bq so QK^T scores are exp2-ready
#define C2F 0.04508422002778011f

__device__ __forceinline__ u16 f2bf(float f) {
  union { float f; unsigned u; } v; v.f = f;
  unsigned u = v.u;
  return (u16)((u + 0x7FFFu + ((u >> 16) & 1u)) >> 16);  // RNE
}
__device__ __forceinline__ float bf2f(u16 h) {
  union { unsigned u; float f; } v; v.u = ((unsigned)h) << 16;
  return v.f;
}
__device__ __forceinline__ unsigned pk_bf16(float lo, float hi) {
  unsigned r;
  asm volatile("v_cvt_pk_bf16_f32 %0, %1, %2" : "=v"(r) : "v"(lo), "v"(hi));
  return r;  // D[15:0]=bf16(lo), D[31:16]=bf16(hi)
}

typedef __attribute__((address_space(1))) void gvoid;
typedef __attribute__((address_space(3))) void lvoid;
// async global->LDS, 16B/lane; lds base must be wave-uniform (lane*16 implicit)
__device__ __forceinline__ void gload_lds16(const void* g, void* l) {
  __builtin_amdgcn_global_load_lds((gvoid*)(void*)g, (lvoid*)l, 16, 0, 0);
}

__device__ __forceinline__ float gelu_f(float x) {
  float t = tanhf(0.7978845608028654f * (x + 0.044715f * x * x * x));
  return 0.5f * x * (1.0f + t);
}

// ---- fp32 [Rr,Cc] (batched) -> bf16 transposed [Cc,Rr], optional scale ----
__global__ __launch_bounds__(256) void wtrans(const float* __restrict__ in,
                                              u16* __restrict__ out,
                                              int Rr, int Cc, long ibs, long obs,
                                              float scale) {
  __shared__ float tile[32][33];
  const float* ip = in + (size_t)blockIdx.z * ibs;
  u16* op = out + (size_t)blockIdx.z * obs;
  int c0 = blockIdx.x * 32, r0 = blockIdx.y * 32;
  int tx = threadIdx.x & 31, ty = threadIdx.x >> 5;  // 32 x 8
#pragma unroll
  for (int j = 0; j < 32; j += 8)
    tile[ty + j][tx] = ip[(size_t)(r0 + ty + j) * Cc + c0 + tx];
  __syncthreads();
#pragma unroll
  for (int j = 0; j < 32; j += 8)
    op[(size_t)(c0 + ty + j) * Rr + r0 + tx] = f2bf(tile[tx][ty + j] * scale);
}

// ---- flat fp32 -> bf16 -----------------------------------------------------
__global__ __launch_bounds__(256) void wconv(const float* __restrict__ in,
                                             u16* __restrict__ out, int n) {
  int i = (blockIdx.x * 256 + threadIdx.x) * 4;
  if (i < n) {
    float4 v = *(const float4*)&in[i];
    ushort4 o;
    o.x = f2bf(v.x); o.y = f2bf(v.y); o.z = f2bf(v.z); o.w = f2bf(v.w);
    *(ushort4*)&out[i] = o;
  }
}

// ---- LayerNorm (optionally fused residual add + x2 passthrough) -----------
__global__ __launch_bounds__(256) void ln_kernel(const float* __restrict__ xin,
                                                 const float* __restrict__ addin,
                                                 const float* __restrict__ gam,
                                                 const float* __restrict__ bet,
                                                 u16* __restrict__ hout,
                                                 float* __restrict__ x2out) {
  int row = blockIdx.x, tid = threadIdx.x;
  size_t base = (size_t)row * D_ + tid * 4;
  float4 v = *(const float4*)&xin[base];
  if (addin) {
    float4 a = *(const float4*)&addin[base];
    v.x += a.x; v.y += a.y; v.z += a.z; v.w += a.w;
  }
  if (x2out) *(float4*)&x2out[base] = v;
  float s = v.x + v.y + v.z + v.w;
  float ss = v.x * v.x + v.y * v.y + v.z * v.z + v.w * v.w;
#pragma unroll
  for (int off = 32; off > 0; off >>= 1) {
    s += __shfl_down(s, off);
    ss += __shfl_down(ss, off);
  }
  __shared__ float red[8];
  int wv = tid >> 6;
  if ((tid & 63) == 0) { red[wv] = s; red[4 + wv] = ss; }
  __syncthreads();
  if (tid == 0) {
    float s1 = red[0] + red[1] + red[2] + red[3];
    float s2 = red[4] + red[5] + red[6] + red[7];
    float mu = s1 * (1.0f / D_);
    red[0] = mu;
    red[1] = s2 * (1.0f / D_) - mu * mu;
  }
  __syncthreads();
  float mu = red[0];
  float rstd = rsqrtf(red[1] + 1e-5f);
  int ci = tid * 4;
  ushort4 o;
  o.x = f2bf((v.x - mu) * rstd * gam[ci + 0] + bet[ci + 0]);
  o.y = f2bf((v.y - mu) * rstd * gam[ci + 1] + bet[ci + 1]);
  o.z = f2bf((v.z - mu) * rstd * gam[ci + 2] + bet[ci + 2]);
  o.w = f2bf((v.w - mu) * rstd * gam[ci + 3] + bet[ci + 3]);
  *(ushort4*)&hout[base] = o;
}

// ---- NT GEMM: C[m,n] = sum_k A[m,k]*Bt[n,k] (+bias*bscale, +gelu, +res) ---
// 128x128 tile, BK=32, 4 waves (2x2 of 64x64), 16x16x32 MFMA.
// 2-phase dbuf: STAGE(next half) || COMPUTE(cur), 1 barrier/K-step.
// MODE 0: bf16 out + bias; 1: bf16 out + bias + gelu; 2: f32 out + bias + res
template <int MODE>
__global__ __launch_bounds__(256) void gemm_nt(const u16* __restrict__ A,
                                               const u16* __restrict__ Bt,
                                               int K, int lda, int ldb,
                                               const float* __restrict__ bias,
                                               float bscale,
                                               const float* __restrict__ res,
                                               void* __restrict__ Cout, int ldc) {
  __shared__ __align__(16) u16 As0[128 * 32];
  __shared__ __align__(16) u16 Bs0[128 * 32];
  __shared__ __align__(16) u16 As1[128 * 32];
  __shared__ __align__(16) u16 Bs1[128 * 32];
  int tid = threadIdx.x;
  int lane = tid & 63, wid = tid >> 6;
  int wm = wid >> 1, wn = wid & 1;
  int row0 = blockIdx.y * 128, col0 = blockIdx.x * 128;
  int l15 = lane & 15, g = lane >> 4;
  int srow = lane >> 2, scol = (lane & 3) * 8;
  f32x4 acc[4][4] = {};
  const u16* Ap = A + (size_t)row0 * lda;
  const u16* Bp = Bt + (size_t)col0 * ldb;

  auto STAGE = [&](u16* AS, u16* BS, int kk) {
#pragma unroll
    for (int i = 0; i < 2; ++i) {
      int c = wid * 2 + i;  // chunk = 16 rows x 32 cols = 1KB, one wave-load
      gload_lds16(Ap + (size_t)(c * 16 + srow) * lda + kk + scol, &AS[c * 512]);
      gload_lds16(Bp + (size_t)(c * 16 + srow) * ldb + kk + scol, &BS[c * 512]);
    }
  };
  auto COMPUTE = [&](const u16* AS, const u16* BS) {
    bf16x8 af[4], bfr[4];
#pragma unroll
    for (int t = 0; t < 4; ++t) {
      af[t] = *(const bf16x8*)&AS[(wm * 64 + t * 16 + l15) * 32 + g * 8];
      bfr[t] = *(const bf16x8*)&BS[(wn * 64 + t * 16 + l15) * 32 + g * 8];
    }
#pragma unroll
    for (int mt = 0; mt < 4; ++mt)
#pragma unroll
      for (int nt = 0; nt < 4; ++nt)
        acc[mt][nt] = __builtin_amdgcn_mfma_f32_16x16x32_bf16(af[mt], bfr[nt],
                                                              acc[mt][nt], 0, 0, 0);
  };

  STAGE(As0, Bs0, 0);
  __syncthreads();  // drains vmcnt(0): tile 0 ready
  for (int k0 = 0; k0 < K; k0 += 64) {  // K % 64 == 0 for all call sites
    if (k0 + 32 < K) STAGE(As1, Bs1, k0 + 32);
    COMPUTE(As0, Bs0);
    __syncthreads();  // reads of As0 retired + As1 staging drained
    if (k0 + 64 < K) STAGE(As0, Bs0, k0 + 64);
    COMPUTE(As1, Bs1);
    __syncthreads();
  }

  // epilogue: C/D layout col=lane&15, row=(lane>>4)*4+j  [verified m89/m91]
#pragma unroll
  for (int mt = 0; mt < 4; ++mt) {
#pragma unroll
    for (int nt = 0; nt < 4; ++nt) {
      int cc = col0 + wn * 64 + nt * 16 + l15;
      float bv = bias ? bias[cc] * bscale : 0.0f;
#pragma unroll
      for (int j = 0; j < 4; ++j) {
        int rr = row0 + wm * 64 + mt * 16 + g * 4 + j;
        float v = acc[mt][nt][j] + bv;
        if (MODE == 1) v = gelu_f(v);
        if (MODE == 2) {
          ((float*)Cout)[(size_t)rr * ldc + cc] = v + res[(size_t)rr * ldc + cc];
        } else {
          ((u16*)Cout)[(size_t)rr * ldc + cc] = f2bf(v);
        }
      }
    }
  }
}

// ---- low-rank V up-proj -> V^T [b,h][e][t] bf16 ----------------------------
__global__ __launch_bounds__(256) void vu_kernel(const u16* __restrict__ vd,
                                                 const u16* __restrict__ wvu,
                                                 const float* __restrict__ bvu,
                                                 u16* __restrict__ v_t) {
  int t0 = blockIdx.x * 64, h = blockIdx.y, b = blockIdx.z;
  __shared__ u16 vds[64][32];
  __shared__ u16 vt[64][65];
  int tid = threadIdx.x;
  {
    int rr2 = tid >> 2, c8 = (tid & 3) * 8;
    *(bf16x8*)&vds[rr2][c8] =
        *(const bf16x8*)&vd[(size_t)(b * S_ + t0 + rr2) * (H_ * R_) + h * R_ + c8];
  }
  __syncthreads();
  int e = tid & 63, tg = (tid >> 6) * 16;
  float wcol[32];
#pragma unroll
  for (int r = 0; r < 32; ++r) wcol[r] = bf2f(wvu[((size_t)h * R_ + r) * HD_ + e]);
  float bb = bvu[h * HD_ + e];
  for (int i = 0; i < 16; ++i) {
    int t = tg + i;
    float acc = bb;
#pragma unroll
    for (int r = 0; r < 32; ++r) acc += bf2f(vds[t][r]) * wcol[r];
    vt[t][e] = f2bf(acc);
  }
  __syncthreads();
  for (int idx = tid; idx < 64 * 64; idx += 256) {
    int e2 = idx >> 6, t2 = idx & 63;
    v_t[((size_t)(b * H_ + h) * HD_ + e2) * S_ + t0 + t2] = vt[t2][e2];
  }
}

// ---- attention v3: reversed-causal (key t >= query s) ----------------------
// grid (S/128, H, B) = 512 blocks; block handles q-tiles bx*64 and
// S-64-bx*64 sequentially -> uniform 33 steps/block. 4 waves, wave w owns
// 16 queries. Swapped QK^T (rows=keys, cols=queries), per-lane softmax in
// exp2 domain (scale pre-folded into Q), double-buffered K/V LDS staging.
__global__ __launch_bounds__(256) void attn_kernel(const u16* __restrict__ q,
                                                   const u16* __restrict__ k,
                                                   const u16* __restrict__ v_t,
                                                   float* __restrict__ o) {
  int tid = threadIdx.x;
  int lane = tid & 63, w = tid >> 6;
  int h = blockIdx.y, b = blockIdx.z;
  int r = lane & 15, g = lane >> 4;
  const u16* qp = q + (size_t)(b * S_) * D_ + h * HD_;
  const u16* kp = k + (size_t)(b * S_) * D_ + h * HD_;
  const u16* vp = v_t + (size_t)(b * H_ + h) * HD_ * S_;

  __shared__ u16 Ks[2][64 * 64];  // [key][d], rows swizzled
  __shared__ u16 Vs[2][64 * 64];  // [e][key], rows swizzled
  __shared__ u16 Pl[4][16 * 64];  // per-wave P^T [q][key], swizzled
  u16* Pw = Pl[w];

  // staging: wave w owns rows w*16..w*16+15 (2 wave-loads: rows srow, srow+8;
  // (srow+8)&7 == srow&7 so the swizzle byte is identical)
  int srow = w * 16 + (lane >> 3);
  int ssw = ((lane & 7) * 16) ^ (((lane >> 3) & 7) << 4);  // pre-swz byte in row

  int xr = (r & 7) << 4;                // read-side XOR (row = ..*16 + r)
  int kq0 = ((g * 16) ^ xr) >> 1;       // elem offset, k-group 0
  int kq1 = ((64 + g * 16) ^ xr) >> 1;  // elem offset, k-group 1

  auto STAGE = [&](int buf, int kt) {
    gload_lds16((const char*)(kp + (size_t)(kt + srow) * D_) + ssw,
                &Ks[buf][w * 1024]);
    gload_lds16((const char*)(kp + (size_t)(kt + srow + 8) * D_) + ssw,
                &Ks[buf][w * 1024 + 512]);
    gload_lds16((const char*)(vp + (size_t)srow * S_ + kt) + ssw,
                &Vs[buf][w * 1024]);
    gload_lds16((const char*)(vp + (size_t)(srow + 8) * S_ + kt) + ssw,
                &Vs[buf][w * 1024 + 512]);
  };

#pragma unroll 1
  for (int half = 0; half < 2; ++half) {
    int qb = half ? (S_ - 64) - blockIdx.x * 64 : blockIdx.x * 64;
    int s0 = qb + w * 16;
    int qrow = s0 + r;

    // Q B-frags (pre-scaled by C2F via WqT/bq): col q = r, d = kg*32 + g*8
    bf16x8 aq0 = *(const bf16x8*)(qp + (size_t)(s0 + r) * D_ + g * 8);
    bf16x8 aq1 = *(const bf16x8*)(qp + (size_t)(s0 + r) * D_ + 32 + g * 8);

    f32x4 oa[4] = {};              // O^T: row e = et*16 + g*4+j, col q = r
    float m_ = -1e30f, l_ = 0.0f;  // per-lane online softmax state (exp2 dom)

    STAGE(0, qb);
    __syncthreads();  // tile 0 ready
    int cur = 0;
    for (int kt = qb; kt < S_; kt += 64) {
      if (kt + 64 < S_) STAGE(cur ^ 1, kt + 64);
      const u16* Kb = &Ks[cur][0];
      const u16* Vb = &Vs[cur][0];

      // QK^T: sc[blk] rows = keys blk*16 + g*4+j, col = query r
      f32x4 sc[4] = {};
#pragma unroll
      for (int blk = 0; blk < 4; ++blk) {
        bf16x8 a0 = *(const bf16x8*)&Kb[((blk * 16 + r) << 6) + kq0];
        bf16x8 a1 = *(const bf16x8*)&Kb[((blk * 16 + r) << 6) + kq1];
        sc[blk] = __builtin_amdgcn_mfma_f32_16x16x32_bf16(a0, aq0, sc[blk], 0, 0, 0);
        sc[blk] = __builtin_amdgcn_mfma_f32_16x16x32_bf16(a1, aq1, sc[blk], 0, 0, 0);
      }

      // mask only on the diagonal tile (all later tiles have kk >= qb+64 > qrow)
      float p[16];
      if (kt == qb) {
#pragma unroll
        for (int blk = 0; blk < 4; ++blk)
#pragma unroll
          for (int j = 0; j < 4; ++j) {
            int kk = kt + blk * 16 + g * 4 + j;
            p[blk * 4 + j] = (kk < qrow) ? -1e30f : sc[blk][j];
          }
      } else {
#pragma unroll
        for (int blk = 0; blk < 4; ++blk)
#pragma unroll
          for (int j = 0; j < 4; ++j) p[blk * 4 + j] = sc[blk][j];
      }
      float mx = p[0];
#pragma unroll
      for (int i = 1; i < 16; ++i) mx = fmaxf(mx, p[i]);
      mx = fmaxf(mx, __shfl_xor(mx, 16));
      mx = fmaxf(mx, __shfl_xor(mx, 32));
      float mn = fmaxf(m_, mx);
      float scl = __builtin_amdgcn_exp2f(m_ - mn);
      m_ = mn;
      float sm = 0.0f;
#pragma unroll
      for (int i = 0; i < 16; ++i) {
        p[i] = __builtin_amdgcn_exp2f(p[i] - mn);
        sm += p[i];
      }
      sm += __shfl_xor(sm, 16);
      sm += __shfl_xor(sm, 32);
      l_ = l_ * scl + sm;
#pragma unroll
      for (int et = 0; et < 4; ++et) oa[et] *= scl;

      // P -> per-wave LDS (bf16, swizzled), read back as PV B-frags
#pragma unroll
      for (int blk = 0; blk < 4; ++blk) {
        uint2 pk;
        pk.x = pk_bf16(p[blk * 4 + 0], p[blk * 4 + 1]);
        pk.y = pk_bf16(p[blk * 4 + 2], p[blk * 4 + 3]);
        *(uint2*)&Pw[(r << 6) + ((((blk << 5) + (g << 3)) ^ xr) >> 1)] = pk;
      }
      asm volatile("s_waitcnt lgkmcnt(0)" ::: "memory");  // P visible in-wave
      bf16x8 pb0 = *(const bf16x8*)&Pw[(r << 6) + kq0];
      bf16x8 pb1 = *(const bf16x8*)&Pw[(r << 6) + kq1];
#pragma unroll
      for (int et = 0; et < 4; ++et) {
        bf16x8 v0 = *(const bf16x8*)&Vb[((et * 16 + r) << 6) + kq0];
        bf16x8 v1 = *(const bf16x8*)&Vb[((et * 16 + r) << 6) + kq1];
        oa[et] = __builtin_amdgcn_mfma_f32_16x16x32_bf16(v0, pb0, oa[et], 0, 0, 0);
        oa[et] = __builtin_amdgcn_mfma_f32_16x16x32_bf16(v1, pb1, oa[et], 0, 0, 0);
      }
      __syncthreads();  // cur reads retired + cur^1 staging drained
      cur ^= 1;
    }

    float inv = 1.0f / l_;
#pragma unroll
    for (int et = 0; et < 4; ++et)
#pragma unroll
      for (int j = 0; j < 4; ++j)
        o[(size_t)(b * S_ + s0 + r) * D_ + h * HD_ + et * 16 + g * 4 + j] =
            oa[et][j] * inv;
  }
}

extern "C" void kernel_launch(void* const* d_in, const int* in_sizes, int n_in,
                              void* d_out, int out_size, void* d_ws, size_t ws_size,
                              hipStream_t stream) {
  const float* x = (const float*)d_in[0];
  const float* ln1_g = (const float*)d_in[1];
  const float* ln1_b = (const float*)d_in[2];
  const float* Wq = (const float*)d_in[3];
  const float* bq = (const float*)d_in[4];
  const float* Wk = (const float*)d_in[5];
  const float* bk = (const float*)d_in[6];
  const float* Wvd = (const float*)d_in[7];
  const float* bvd = (const float*)d_in[8];
  const float* Wvu = (const float*)d_in[9];
  const float* bvu = (const float*)d_in[10];
  const float* ln2_g = (const float*)d_in[11];
  const float* ln2_b = (const float*)d_in[12];
  const float* W1 = (const float*)d_in[13];
  const float* b1 = (const float*)d_in[14];
  const float* W2 = (const float*)d_in[15];
  const float* b2 = (const float*)d_in[16];
  float* out = (float*)d_out;
  (void)in_sizes; (void)n_in; (void)out_size; (void)ws_size;

  char* ws = (char*)d_ws;
  const size_t MB = 1024 * 1024;
  u16* wqT = (u16*)(ws + 0);
  u16* wkT = (u16*)(ws + 2 * MB);
  u16* wvdT = (u16*)(ws + 4 * MB);
  u16* wvuB = (u16*)(ws + 5 * MB);
  u16* w1T = (u16*)(ws + 5 * MB + 256 * 1024);
  u16* w2T = (u16*)(ws + 13 * MB + 256 * 1024);
  u16* hbuf = (u16*)(ws + 21 * MB + 256 * 1024);
  u16* qall = (u16*)(ws + 29 * MB + 256 * 1024);
  u16* kall = (u16*)(ws + 37 * MB + 256 * 1024);
  u16* vdall = (u16*)(ws + 45 * MB + 256 * 1024);
  u16* vT = (u16*)(ws + 49 * MB + 256 * 1024);
  float* ob = (float*)(ws + 57 * MB + 256 * 1024);
  float* x2 = (float*)(ws + 73 * MB + 256 * 1024);
  u16* ubuf = qall;

  dim3 blk(256);
  wtrans<<<dim3(2, 32, 16), blk, 0, stream>>>(Wq, wqT, 1024, 64, 65536L, 65536L, C2F);
  wtrans<<<dim3(2, 32, 16), blk, 0, stream>>>(Wk, wkT, 1024, 64, 65536L, 65536L, 1.0f);
  wtrans<<<dim3(1, 32, 16), blk, 0, stream>>>(Wvd, wvdT, 1024, 32, 32768L, 32768L, 1.0f);
  wconv<<<dim3(32), blk, 0, stream>>>(Wvu, wvuB, H_ * R_ * HD_);
  wtrans<<<dim3(128, 32, 1), blk, 0, stream>>>(W1, w1T, 1024, 4096, 0L, 0L, 1.0f);
  wtrans<<<dim3(32, 128, 1), blk, 0, stream>>>(W2, w2T, 4096, 1024, 0L, 0L, 1.0f);
  ln_kernel<<<dim3(M_), blk, 0, stream>>>(x, (const float*)nullptr, ln1_g, ln1_b,
                                          hbuf, (float*)nullptr);
  gemm_nt<0><<<dim3(8, 32), blk, 0, stream>>>(hbuf, wqT, 1024, 1024, 1024, bq, C2F,
                                              (const float*)nullptr, (void*)qall, 1024);
  gemm_nt<0><<<dim3(8, 32), blk, 0, stream>>>(hbuf, wkT, 1024, 1024, 1024, bk, 1.0f,
                                              (const float*)nullptr, (void*)kall, 1024);
  gemm_nt<0><<<dim3(4, 32), blk, 0, stream>>>(hbuf, wvdT, 1024, 1024, 1024, bvd, 1.0f,
                                              (const float*)nullptr, (void*)vdall, 512);
  vu_kernel<<<dim3(S_ / 64, H_, B_), blk, 0, stream>>>(vdall, wvuB, bvu, vT);
  attn_kernel<<<dim3(S_ / 128, H_, B_), blk, 0, stream>>>(qall, kall, vT, ob);
  ln_kernel<<<dim3(M_), blk, 0, stream>>>(x, ob, ln2_g, ln2_b, hbuf, x2);
  gemm_nt<1><<<dim3(32, 32), blk, 0, stream>>>(hbuf, w1T, 1024, 1024, 1024, b1, 1.0f,
                                               (const float*)nullptr, (void*)ubuf, 4096);
  gemm_nt<2><<<dim3(8, 32), blk, 0, stream>>>(ubuf, w2T, 4096, 4096, 4096, b2, 1.0f, x2,
                                              (void*)out, 1024);
}

// Round 6
// 261.609 us; speedup vs baseline: 2.0164x; 1.1364x over previous
//
#include <hip/hip_runtime.h>

// ---------------------------------------------------------------------------
// TransformerBlock: LN1 -> QKV proj (fused) -> reversed-causal attention
// (scale 1/sqrt(D)=1/32) -> residual -> LN2 -> GELU FFN -> residual.
// B=2 S=2048 D=1024 H=16 HD=64 R=32 F=4096. All d_in/d_out fp32; internal
// compute bf16 MFMA.
// R5: occupancy fixes for the 1-block/CU GEMMs —
//   * Q/K/Vd fused into ONE gemm: Bt = [WqT|WkT|WvdT] (N=2560), out cqkv
//     [4096x2560], grid 640 blocks (2.5/CU). Biases concatenated (bq pre-
//     scaled by C2F).
//   * FFN2 split-K=2 in one launch (grid z=2): z=0 -> f32 partial straight
//     into d_out, z=1 -> bf16 partial into dead ws; reduce adds p1+b2+x2.
// ---------------------------------------------------------------------------

typedef unsigned short u16;
typedef __attribute__((ext_vector_type(4))) float f32x4;
typedef __attribute__((ext_vector_type(8))) __bf16 bf16x8;

#define B_ 2
#define S_ 2048
#define D_ 1024
#define H_ 16
#define HD_ 64
#define R_ 32
#define F_ 4096
#define M_ (B_ * S_)   // 4096 rows
#define NQKV 2560      // 1024 q + 1024 k + 512 vd
// (1/sqrt(D)) * log2(e): folded into Wq/bq so QK^T scores are exp2-ready
#define C2F 0.04508422002778011f

__device__ __forceinline__ u16 f2bf(float f) {
  union { float f; unsigned u; } v; v.f = f;
  unsigned u = v.u;
  return (u16)((u + 0x7FFFu + ((u >> 16) & 1u)) >> 16);  // RNE
}
__device__ __forceinline__ float bf2f(u16 h) {
  union { unsigned u; float f; } v; v.u = ((unsigned)h) << 16;
  return v.f;
}
__device__ __forceinline__ unsigned pk_bf16(float lo, float hi) {
  unsigned r;
  asm volatile("v_cvt_pk_bf16_f32 %0, %1, %2" : "=v"(r) : "v"(lo), "v"(hi));
  return r;  // D[15:0]=bf16(lo), D[31:16]=bf16(hi)
}

typedef __attribute__((address_space(1))) void gvoid;
typedef __attribute__((address_space(3))) void lvoid;
// async global->LDS, 16B/lane; lds base must be wave-uniform (lane*16 implicit)
__device__ __forceinline__ void gload_lds16(const void* g, void* l) {
  __builtin_amdgcn_global_load_lds((gvoid*)(void*)g, (lvoid*)l, 16, 0, 0);
}

__device__ __forceinline__ float gelu_f(float x) {
  float t = tanhf(0.7978845608028654f * (x + 0.044715f * x * x * x));
  return 0.5f * x * (1.0f + t);
}

// ---- fp32 [Rr,Cc] (batched) -> bf16 transposed [Cc,Rr], optional scale ----
__global__ __launch_bounds__(256) void wtrans(const float* __restrict__ in,
                                              u16* __restrict__ out,
                                              int Rr, int Cc, long ibs, long obs,
                                              float scale) {
  __shared__ float tile[32][33];
  const float* ip = in + (size_t)blockIdx.z * ibs;
  u16* op = out + (size_t)blockIdx.z * obs;
  int c0 = blockIdx.x * 32, r0 = blockIdx.y * 32;
  int tx = threadIdx.x & 31, ty = threadIdx.x >> 5;  // 32 x 8
#pragma unroll
  for (int j = 0; j < 32; j += 8)
    tile[ty + j][tx] = ip[(size_t)(r0 + ty + j) * Cc + c0 + tx];
  __syncthreads();
#pragma unroll
  for (int j = 0; j < 32; j += 8)
    op[(size_t)(c0 + ty + j) * Rr + r0 + tx] = f2bf(tile[tx][ty + j] * scale);
}

// ---- flat fp32 -> bf16 -----------------------------------------------------
__global__ __launch_bounds__(256) void wconv(const float* __restrict__ in,
                                             u16* __restrict__ out, int n) {
  int i = (blockIdx.x * 256 + threadIdx.x) * 4;
  if (i < n) {
    float4 v = *(const float4*)&in[i];
    ushort4 o;
    o.x = f2bf(v.x); o.y = f2bf(v.y); o.z = f2bf(v.z); o.w = f2bf(v.w);
    *(ushort4*)&out[i] = o;
  }
}

// ---- concat biases: [bq*C2F | bk | bvd] -> bqkv[2560] ----------------------
__global__ __launch_bounds__(256) void bconcat(const float* __restrict__ bq,
                                               const float* __restrict__ bk,
                                               const float* __restrict__ bvd,
                                               float* __restrict__ o) {
  int i = blockIdx.x * 256 + threadIdx.x;
  if (i < NQKV) {
    float v = (i < 1024) ? bq[i] * C2F : (i < 2048 ? bk[i - 1024] : bvd[i - 2048]);
    o[i] = v;
  }
}

// ---- LayerNorm (optionally fused residual add + x2 passthrough) -----------
__global__ __launch_bounds__(256) void ln_kernel(const float* __restrict__ xin,
                                                 const float* __restrict__ addin,
                                                 const float* __restrict__ gam,
                                                 const float* __restrict__ bet,
                                                 u16* __restrict__ hout,
                                                 float* __restrict__ x2out) {
  int row = blockIdx.x, tid = threadIdx.x;
  size_t base = (size_t)row * D_ + tid * 4;
  float4 v = *(const float4*)&xin[base];
  if (addin) {
    float4 a = *(const float4*)&addin[base];
    v.x += a.x; v.y += a.y; v.z += a.z; v.w += a.w;
  }
  if (x2out) *(float4*)&x2out[base] = v;
  float s = v.x + v.y + v.z + v.w;
  float ss = v.x * v.x + v.y * v.y + v.z * v.z + v.w * v.w;
#pragma unroll
  for (int off = 32; off > 0; off >>= 1) {
    s += __shfl_down(s, off);
    ss += __shfl_down(ss, off);
  }
  __shared__ float red[8];
  int wv = tid >> 6;
  if ((tid & 63) == 0) { red[wv] = s; red[4 + wv] = ss; }
  __syncthreads();
  if (tid == 0) {
    float s1 = red[0] + red[1] + red[2] + red[3];
    float s2 = red[4] + red[5] + red[6] + red[7];
    float mu = s1 * (1.0f / D_);
    red[0] = mu;
    red[1] = s2 * (1.0f / D_) - mu * mu;
  }
  __syncthreads();
  float mu = red[0];
  float rstd = rsqrtf(red[1] + 1e-5f);
  int ci = tid * 4;
  ushort4 o;
  o.x = f2bf((v.x - mu) * rstd * gam[ci + 0] + bet[ci + 0]);
  o.y = f2bf((v.y - mu) * rstd * gam[ci + 1] + bet[ci + 1]);
  o.z = f2bf((v.z - mu) * rstd * gam[ci + 2] + bet[ci + 2]);
  o.w = f2bf((v.w - mu) * rstd * gam[ci + 3] + bet[ci + 3]);
  *(ushort4*)&hout[base] = o;
}

// ---- NT GEMM: C[m,n] = sum_k A[m,k]*Bt[n,k] (+bias, +gelu, +res) ----------
// 128x128 tile, BK=32, 4 waves (2x2 of 64x64), 16x16x32 MFMA.
// 2-phase dbuf: STAGE(next half) || COMPUTE(cur), 1 barrier/K-step.
// MODE 0: bf16 out + bias; 1: bf16 + bias + gelu; 2: f32 + bias + res;
// MODE 4: split-K (blockIdx.z: 0 -> f32 raw to Cout, 1 -> bf16 raw to Cout2)
template <int MODE>
__global__ __launch_bounds__(256) void gemm_nt(const u16* __restrict__ A,
                                               const u16* __restrict__ Bt,
                                               int K, int lda, int ldb,
                                               const float* __restrict__ bias,
                                               const float* __restrict__ res,
                                               void* __restrict__ Cout,
                                               void* __restrict__ Cout2, int ldc) {
  __shared__ __align__(16) u16 As0[128 * 32];
  __shared__ __align__(16) u16 Bs0[128 * 32];
  __shared__ __align__(16) u16 As1[128 * 32];
  __shared__ __align__(16) u16 Bs1[128 * 32];
  int tid = threadIdx.x;
  int lane = tid & 63, wid = tid >> 6;
  int wm = wid >> 1, wn = wid & 1;
  int row0 = blockIdx.y * 128, col0 = blockIdx.x * 128;
  int koff = (MODE == 4) ? blockIdx.z * K : 0;
  int l15 = lane & 15, g = lane >> 4;
  int srow = lane >> 2, scol = (lane & 3) * 8;
  f32x4 acc[4][4] = {};
  const u16* Ap = A + (size_t)row0 * lda + koff;
  const u16* Bp = Bt + (size_t)col0 * ldb + koff;

  auto STAGE = [&](u16* AS, u16* BS, int kk) {
#pragma unroll
    for (int i = 0; i < 2; ++i) {
      int c = wid * 2 + i;  // chunk = 16 rows x 32 cols = 1KB, one wave-load
      gload_lds16(Ap + (size_t)(c * 16 + srow) * lda + kk + scol, &AS[c * 512]);
      gload_lds16(Bp + (size_t)(c * 16 + srow) * ldb + kk + scol, &BS[c * 512]);
    }
  };
  auto COMPUTE = [&](const u16* AS, const u16* BS) {
    bf16x8 af[4], bfr[4];
#pragma unroll
    for (int t = 0; t < 4; ++t) {
      af[t] = *(const bf16x8*)&AS[(wm * 64 + t * 16 + l15) * 32 + g * 8];
      bfr[t] = *(const bf16x8*)&BS[(wn * 64 + t * 16 + l15) * 32 + g * 8];
    }
#pragma unroll
    for (int mt = 0; mt < 4; ++mt)
#pragma unroll
      for (int nt = 0; nt < 4; ++nt)
        acc[mt][nt] = __builtin_amdgcn_mfma_f32_16x16x32_bf16(af[mt], bfr[nt],
                                                              acc[mt][nt], 0, 0, 0);
  };

  STAGE(As0, Bs0, 0);
  __syncthreads();  // drains vmcnt(0): tile 0 ready
  for (int k0 = 0; k0 < K; k0 += 64) {  // K % 64 == 0 for all call sites
    if (k0 + 32 < K) STAGE(As1, Bs1, k0 + 32);
    COMPUTE(As0, Bs0);
    __syncthreads();  // reads of As0 retired + As1 staging drained
    if (k0 + 64 < K) STAGE(As0, Bs0, k0 + 64);
    COMPUTE(As1, Bs1);
    __syncthreads();
  }

  // epilogue: C/D layout col=lane&15, row=(lane>>4)*4+j  [verified m89/m91]
#pragma unroll
  for (int mt = 0; mt < 4; ++mt) {
#pragma unroll
    for (int nt = 0; nt < 4; ++nt) {
      int cc = col0 + wn * 64 + nt * 16 + l15;
      float bv = (MODE != 4 && bias) ? bias[cc] : 0.0f;
#pragma unroll
      for (int j = 0; j < 4; ++j) {
        int rr = row0 + wm * 64 + mt * 16 + g * 4 + j;
        float v = acc[mt][nt][j] + bv;
        if (MODE == 1) v = gelu_f(v);
        if (MODE == 2) {
          ((float*)Cout)[(size_t)rr * ldc + cc] = v + res[(size_t)rr * ldc + cc];
        } else if (MODE == 4) {
          if (blockIdx.z == 0)
            ((float*)Cout)[(size_t)rr * ldc + cc] = v;
          else
            ((u16*)Cout2)[(size_t)rr * ldc + cc] = f2bf(v);
        } else {
          ((u16*)Cout)[(size_t)rr * ldc + cc] = f2bf(v);
        }
      }
    }
  }
}

// ---- split-K reduce: out += bf2f(p1) + b2[col] + x2 ------------------------
__global__ __launch_bounds__(256) void reduce2(float* __restrict__ out,
                                               const u16* __restrict__ p1,
                                               const float* __restrict__ b2,
                                               const float* __restrict__ x2) {
  int i = (blockIdx.x * 256 + threadIdx.x) * 4;
  float4 o = *(float4*)&out[i];
  ushort4 p = *(const ushort4*)&p1[i];
  float4 r = *(const float4*)&x2[i];
  int c = i & (D_ - 1);
  o.x += bf2f(p.x) + b2[c + 0] + r.x;
  o.y += bf2f(p.y) + b2[c + 1] + r.y;
  o.z += bf2f(p.z) + b2[c + 2] + r.z;
  o.w += bf2f(p.w) + b2[c + 3] + r.w;
  *(float4*)&out[i] = o;
}

// ---- low-rank V up-proj -> V^T [b,h][e][t] bf16 ----------------------------
// vd lives in cqkv at col offset 2048, row stride NQKV
__global__ __launch_bounds__(256) void vu_kernel(const u16* __restrict__ vd,
                                                 const u16* __restrict__ wvu,
                                                 const float* __restrict__ bvu,
                                                 u16* __restrict__ v_t) {
  int t0 = blockIdx.x * 64, h = blockIdx.y, b = blockIdx.z;
  __shared__ u16 vds[64][32];
  __shared__ u16 vt[64][65];
  int tid = threadIdx.x;
  {
    int rr2 = tid >> 2, c8 = (tid & 3) * 8;
    *(bf16x8*)&vds[rr2][c8] =
        *(const bf16x8*)&vd[(size_t)(b * S_ + t0 + rr2) * NQKV + 2048 + h * R_ + c8];
  }
  __syncthreads();
  int e = tid & 63, tg = (tid >> 6) * 16;
  float wcol[32];
#pragma unroll
  for (int r = 0; r < 32; ++r) wcol[r] = bf2f(wvu[((size_t)h * R_ + r) * HD_ + e]);
  float bb = bvu[h * HD_ + e];
  for (int i = 0; i < 16; ++i) {
    int t = tg + i;
    float acc = bb;
#pragma unroll
    for (int r = 0; r < 32; ++r) acc += bf2f(vds[t][r]) * wcol[r];
    vt[t][e] = f2bf(acc);
  }
  __syncthreads();
  for (int idx = tid; idx < 64 * 64; idx += 256) {
    int e2 = idx >> 6, t2 = idx & 63;
    v_t[((size_t)(b * H_ + h) * HD_ + e2) * S_ + t0 + t2] = vt[t2][e2];
  }
}

// ---- attention: reversed-causal (key t >= query s) -------------------------
// grid (S/128, H, B) = 512 blocks; block handles q-tiles bx*64 and
// S-64-bx*64 sequentially -> uniform 33 steps/block. 4 waves, wave w owns
// 16 queries. Swapped QK^T (rows=keys, cols=queries), per-lane softmax in
// exp2 domain (scale pre-folded into Q), double-buffered K/V LDS staging.
// q/k read from cqkv (row stride NQKV; k at col offset 1024).
__global__ __launch_bounds__(256) void attn_kernel(const u16* __restrict__ cqkv,
                                                   const u16* __restrict__ v_t,
                                                   float* __restrict__ o) {
  int tid = threadIdx.x;
  int lane = tid & 63, w = tid >> 6;
  int h = blockIdx.y, b = blockIdx.z;
  int r = lane & 15, g = lane >> 4;
  const u16* qp = cqkv + (size_t)(b * S_) * NQKV + h * HD_;
  const u16* kp = cqkv + (size_t)(b * S_) * NQKV + 1024 + h * HD_;
  const u16* vp = v_t + (size_t)(b * H_ + h) * HD_ * S_;

  __shared__ u16 Ks[2][64 * 64];  // [key][d], rows swizzled
  __shared__ u16 Vs[2][64 * 64];  // [e][key], rows swizzled
  __shared__ u16 Pl[4][16 * 64];  // per-wave P^T [q][key], swizzled
  u16* Pw = Pl[w];

  // staging: wave w owns rows w*16..w*16+15 (2 wave-loads: rows srow, srow+8;
  // (srow+8)&7 == srow&7 so the swizzle byte is identical)
  int srow = w * 16 + (lane >> 3);
  int ssw = ((lane & 7) * 16) ^ (((lane >> 3) & 7) << 4);  // pre-swz byte in row

  int xr = (r & 7) << 4;                // read-side XOR (row = ..*16 + r)
  int kq0 = ((g * 16) ^ xr) >> 1;       // elem offset, k-group 0
  int kq1 = ((64 + g * 16) ^ xr) >> 1;  // elem offset, k-group 1

  auto STAGE = [&](int buf, int kt) {
    gload_lds16((const char*)(kp + (size_t)(kt + srow) * NQKV) + ssw,
                &Ks[buf][w * 1024]);
    gload_lds16((const char*)(kp + (size_t)(kt + srow + 8) * NQKV) + ssw,
                &Ks[buf][w * 1024 + 512]);
    gload_lds16((const char*)(vp + (size_t)srow * S_ + kt) + ssw,
                &Vs[buf][w * 1024]);
    gload_lds16((const char*)(vp + (size_t)(srow + 8) * S_ + kt) + ssw,
                &Vs[buf][w * 1024 + 512]);
  };

#pragma unroll 1
  for (int half = 0; half < 2; ++half) {
    int qb = half ? (S_ - 64) - blockIdx.x * 64 : blockIdx.x * 64;
    int s0 = qb + w * 16;
    int qrow = s0 + r;

    // Q B-frags (pre-scaled by C2F via WqT/bq): col q = r, d = kg*32 + g*8
    bf16x8 aq0 = *(const bf16x8*)(qp + (size_t)(s0 + r) * NQKV + g * 8);
    bf16x8 aq1 = *(const bf16x8*)(qp + (size_t)(s0 + r) * NQKV + 32 + g * 8);

    f32x4 oa[4] = {};              // O^T: row e = et*16 + g*4+j, col q = r
    float m_ = -1e30f, l_ = 0.0f;  // per-lane online softmax state (exp2 dom)

    STAGE(0, qb);
    __syncthreads();  // tile 0 ready
    int cur = 0;
    for (int kt = qb; kt < S_; kt += 64) {
      if (kt + 64 < S_) STAGE(cur ^ 1, kt + 64);
      const u16* Kb = &Ks[cur][0];
      const u16* Vb = &Vs[cur][0];

      // QK^T: sc[blk] rows = keys blk*16 + g*4+j, col = query r
      f32x4 sc[4] = {};
#pragma unroll
      for (int blk = 0; blk < 4; ++blk) {
        bf16x8 a0 = *(const bf16x8*)&Kb[((blk * 16 + r) << 6) + kq0];
        bf16x8 a1 = *(const bf16x8*)&Kb[((blk * 16 + r) << 6) + kq1];
        sc[blk] = __builtin_amdgcn_mfma_f32_16x16x32_bf16(a0, aq0, sc[blk], 0, 0, 0);
        sc[blk] = __builtin_amdgcn_mfma_f32_16x16x32_bf16(a1, aq1, sc[blk], 0, 0, 0);
      }

      // mask only on the diagonal tile (all later tiles have kk >= qb+64 > qrow)
      float p[16];
      if (kt == qb) {
#pragma unroll
        for (int blk = 0; blk < 4; ++blk)
#pragma unroll
          for (int j = 0; j < 4; ++j) {
            int kk = kt + blk * 16 + g * 4 + j;
            p[blk * 4 + j] = (kk < qrow) ? -1e30f : sc[blk][j];
          }
      } else {
#pragma unroll
        for (int blk = 0; blk < 4; ++blk)
#pragma unroll
          for (int j = 0; j < 4; ++j) p[blk * 4 + j] = sc[blk][j];
      }
      float mx = p[0];
#pragma unroll
      for (int i = 1; i < 16; ++i) mx = fmaxf(mx, p[i]);
      mx = fmaxf(mx, __shfl_xor(mx, 16));
      mx = fmaxf(mx, __shfl_xor(mx, 32));
      float mn = fmaxf(m_, mx);
      float scl = __builtin_amdgcn_exp2f(m_ - mn);
      m_ = mn;
      float sm = 0.0f;
#pragma unroll
      for (int i = 0; i < 16; ++i) {
        p[i] = __builtin_amdgcn_exp2f(p[i] - mn);
        sm += p[i];
      }
      sm += __shfl_xor(sm, 16);
      sm += __shfl_xor(sm, 32);
      l_ = l_ * scl + sm;
#pragma unroll
      for (int et = 0; et < 4; ++et) oa[et] *= scl;

      // P -> per-wave LDS (bf16, swizzled), read back as PV B-frags
#pragma unroll
      for (int blk = 0; blk < 4; ++blk) {
        uint2 pk;
        pk.x = pk_bf16(p[blk * 4 + 0], p[blk * 4 + 1]);
        pk.y = pk_bf16(p[blk * 4 + 2], p[blk * 4 + 3]);
        *(uint2*)&Pw[(r << 6) + ((((blk << 5) + (g << 3)) ^ xr) >> 1)] = pk;
      }
      asm volatile("s_waitcnt lgkmcnt(0)" ::: "memory");  // P visible in-wave
      bf16x8 pb0 = *(const bf16x8*)&Pw[(r << 6) + kq0];
      bf16x8 pb1 = *(const bf16x8*)&Pw[(r << 6) + kq1];
#pragma unroll
      for (int et = 0; et < 4; ++et) {
        bf16x8 v0 = *(const bf16x8*)&Vb[((et * 16 + r) << 6) + kq0];
        bf16x8 v1 = *(const bf16x8*)&Vb[((et * 16 + r) << 6) + kq1];
        oa[et] = __builtin_amdgcn_mfma_f32_16x16x32_bf16(v0, pb0, oa[et], 0, 0, 0);
        oa[et] = __builtin_amdgcn_mfma_f32_16x16x32_bf16(v1, pb1, oa[et], 0, 0, 0);
      }
      __syncthreads();  // cur reads retired + cur^1 staging drained
      cur ^= 1;
    }

    float inv = 1.0f / l_;
#pragma unroll
    for (int et = 0; et < 4; ++et)
#pragma unroll
      for (int j = 0; j < 4; ++j)
        o[(size_t)(b * S_ + s0 + r) * D_ + h * HD_ + et * 16 + g * 4 + j] =
            oa[et][j] * inv;
  }
}

extern "C" void kernel_launch(void* const* d_in, const int* in_sizes, int n_in,
                              void* d_out, int out_size, void* d_ws, size_t ws_size,
                              hipStream_t stream) {
  const float* x = (const float*)d_in[0];
  const float* ln1_g = (const float*)d_in[1];
  const float* ln1_b = (const float*)d_in[2];
  const float* Wq = (const float*)d_in[3];
  const float* bq = (const float*)d_in[4];
  const float* Wk = (const float*)d_in[5];
  const float* bk = (const float*)d_in[6];
  const float* Wvd = (const float*)d_in[7];
  const float* bvd = (const float*)d_in[8];
  const float* Wvu = (const float*)d_in[9];
  const float* bvu = (const float*)d_in[10];
  const float* ln2_g = (const float*)d_in[11];
  const float* ln2_b = (const float*)d_in[12];
  const float* W1 = (const float*)d_in[13];
  const float* b1 = (const float*)d_in[14];
  const float* W2 = (const float*)d_in[15];
  const float* b2 = (const float*)d_in[16];
  float* out = (float*)d_out;
  (void)in_sizes; (void)n_in; (void)out_size; (void)ws_size;

  char* ws = (char*)d_ws;
  const size_t MB = 1024 * 1024;
  const size_t KB = 1024;
  // ws map (max 89.375 MB, same footprint as R4):
  u16* wqkvT = (u16*)(ws + 0);                    // [2560x1024] bf16, 5 MB
  u16* wvuB = (u16*)(ws + 5 * MB);                // 64 KB
  float* bqkv = (float*)(ws + 5 * MB + 64 * KB);  // 10 KB
  u16* w1T = (u16*)(ws + 5 * MB + 384 * KB);      // 8 MB -> 13.375
  u16* w2T = (u16*)(ws + 13 * MB + 384 * KB);     // 8 MB -> 21.375
  u16* hbuf = (u16*)(ws + 21 * MB + 384 * KB);    // 8 MB -> 29.375
  u16* cqkv = (u16*)(ws + 29 * MB + 384 * KB);    // 20 MB -> 49.375
  u16* vT = (u16*)(ws + 49 * MB + 384 * KB);      // 8 MB -> 57.375
  float* ob = (float*)(ws + 57 * MB + 384 * KB);  // 16 MB -> 73.375
  float* x2 = (float*)(ws + 73 * MB + 384 * KB);  // 16 MB -> 89.375
  // reuses (lifetime-disjoint):
  u16* ubuf = cqkv;        // 32 MB: cqkv(20)+vT(8)+ob[0:4MB], all dead by FFN1
  u16* p1 = (u16*)(ws + 0);  // 8 MB: wqkvT/wvuB/bqkv/w1T[0:2.6MB], dead by FFN2

  dim3 blk(256);
  // weights: transpose+convert (Q-part scaled by C2F)
  wtrans<<<dim3(2, 32, 16), blk, 0, stream>>>(Wq, wqkvT, 1024, 64, 65536L, 65536L, C2F);
  wtrans<<<dim3(2, 32, 16), blk, 0, stream>>>(Wk, wqkvT + 1024 * 1024, 1024, 64,
                                              65536L, 65536L, 1.0f);
  wtrans<<<dim3(1, 32, 16), blk, 0, stream>>>(Wvd, wqkvT + 2048 * 1024, 1024, 32,
                                              32768L, 32768L, 1.0f);
  wconv<<<dim3(32), blk, 0, stream>>>(Wvu, wvuB, H_ * R_ * HD_);
  bconcat<<<dim3(10), blk, 0, stream>>>(bq, bk, bvd, bqkv);
  wtrans<<<dim3(128, 32, 1), blk, 0, stream>>>(W1, w1T, 1024, 4096, 0L, 0L, 1.0f);
  wtrans<<<dim3(32, 128, 1), blk, 0, stream>>>(W2, w2T, 4096, 1024, 0L, 0L, 1.0f);
  // LN1
  ln_kernel<<<dim3(M_), blk, 0, stream>>>(x, (const float*)nullptr, ln1_g, ln1_b,
                                          hbuf, (float*)nullptr);
  // fused QKV projection: [4096,2560] = hbuf @ [WqT|WkT|WvdT]^T
  gemm_nt<0><<<dim3(20, 32), blk, 0, stream>>>(hbuf, wqkvT, 1024, 1024, 1024, bqkv,
                                               (const float*)nullptr, (void*)cqkv,
                                               (void*)nullptr, NQKV);
  vu_kernel<<<dim3(S_ / 64, H_, B_), blk, 0, stream>>>(cqkv, wvuB, bvu, vT);
  attn_kernel<<<dim3(S_ / 128, H_, B_), blk, 0, stream>>>(cqkv, vT, ob);
  // LN2 with fused residual (x2 = x + attn_out)
  ln_kernel<<<dim3(M_), blk, 0, stream>>>(x, ob, ln2_g, ln2_b, hbuf, x2);
  // FFN1 (gelu)
  gemm_nt<1><<<dim3(32, 32), blk, 0, stream>>>(hbuf, w1T, 1024, 1024, 1024, b1,
                                               (const float*)nullptr, (void*)ubuf,
                                               (void*)nullptr, 4096);
  // FFN2 split-K=2: z=0 -> f32 partial into out, z=1 -> bf16 partial into p1
  gemm_nt<4><<<dim3(8, 32, 2), blk, 0, stream>>>(ubuf, w2T, 2048, 4096, 4096,
                                                 (const float*)nullptr,
                                                 (const float*)nullptr, (void*)out,
                                                 (void*)p1, 1024);
  // out += bf2f(p1) + b2 + x2
  reduce2<<<dim3(M_ * D_ / 1024), blk, 0, stream>>>(out, p1, b2, x2);
}

// Round 7
// 241.579 us; speedup vs baseline: 2.1836x; 1.0829x over previous
//
#include <hip/hip_runtime.h>

// ---------------------------------------------------------------------------
// TransformerBlock: LN1 -> QKV proj (fused) -> reversed-causal attention
// (scale 1/sqrt(D)=1/32) -> residual -> LN2 -> GELU FFN -> residual.
// B=2 S=2048 D=1024 H=16 HD=64 R=32 F=4096. All d_in/d_out fp32; internal
// compute bf16 MFMA.
// R6: gemm8 — 256x256 tile, BK=64, 8 waves (2Mx4N), 128KB dynamic LDS dbuf,
// XOR-swizzled LDS (byte ^= (row&7)<<4 both sides), stage-issues interleaved
// between MFMA half-clusters, ONE vmcnt(0)+s_barrier per K-step, setprio(1)
// around MFMA. Used for FFN1 (16x16 grid = 1 block/CU) and FFN2 split-K=4
// (4x16x4; z=0 -> f32 into out, z=1..3 -> bf16 partials; reduce2 sums).
// ---------------------------------------------------------------------------

typedef unsigned short u16;
typedef __attribute__((ext_vector_type(4))) float f32x4;
typedef __attribute__((ext_vector_type(8))) __bf16 bf16x8;

#define B_ 2
#define S_ 2048
#define D_ 1024
#define H_ 16
#define HD_ 64
#define R_ 32
#define F_ 4096
#define M_ (B_ * S_)   // 4096 rows
#define NQKV 2560      // 1024 q + 1024 k + 512 vd
// (1/sqrt(D)) * log2(e): folded into Wq/bq so QK^T scores are exp2-ready
#define C2F 0.04508422002778011f

__device__ __forceinline__ u16 f2bf(float f) {
  union { float f; unsigned u; } v; v.f = f;
  unsigned u = v.u;
  return (u16)((u + 0x7FFFu + ((u >> 16) & 1u)) >> 16);  // RNE
}
__device__ __forceinline__ float bf2f(u16 h) {
  union { unsigned u; float f; } v; v.u = ((unsigned)h) << 16;
  return v.f;
}
__device__ __forceinline__ unsigned pk_bf16(float lo, float hi) {
  unsigned r;
  asm volatile("v_cvt_pk_bf16_f32 %0, %1, %2" : "=v"(r) : "v"(lo), "v"(hi));
  return r;
}

typedef __attribute__((address_space(1))) void gvoid;
typedef __attribute__((address_space(3))) void lvoid;
// async global->LDS, 16B/lane; lds base must be wave-uniform (lane*16 implicit)
__device__ __forceinline__ void gload_lds16(const void* g, void* l) {
  __builtin_amdgcn_global_load_lds((gvoid*)(void*)g, (lvoid*)l, 16, 0, 0);
}

__device__ __forceinline__ float gelu_f(float x) {
  float t = tanhf(0.7978845608028654f * (x + 0.044715f * x * x * x));
  return 0.5f * x * (1.0f + t);
}

// ---- fp32 [Rr,Cc] (batched) -> bf16 transposed [Cc,Rr], optional scale ----
__global__ __launch_bounds__(256) void wtrans(const float* __restrict__ in,
                                              u16* __restrict__ out,
                                              int Rr, int Cc, long ibs, long obs,
                                              float scale) {
  __shared__ float tile[32][33];
  const float* ip = in + (size_t)blockIdx.z * ibs;
  u16* op = out + (size_t)blockIdx.z * obs;
  int c0 = blockIdx.x * 32, r0 = blockIdx.y * 32;
  int tx = threadIdx.x & 31, ty = threadIdx.x >> 5;  // 32 x 8
#pragma unroll
  for (int j = 0; j < 32; j += 8)
    tile[ty + j][tx] = ip[(size_t)(r0 + ty + j) * Cc + c0 + tx];
  __syncthreads();
#pragma unroll
  for (int j = 0; j < 32; j += 8)
    op[(size_t)(c0 + ty + j) * Rr + r0 + tx] = f2bf(tile[tx][ty + j] * scale);
}

// ---- flat fp32 -> bf16 -----------------------------------------------------
__global__ __launch_bounds__(256) void wconv(const float* __restrict__ in,
                                             u16* __restrict__ out, int n) {
  int i = (blockIdx.x * 256 + threadIdx.x) * 4;
  if (i < n) {
    float4 v = *(const float4*)&in[i];
    ushort4 o;
    o.x = f2bf(v.x); o.y = f2bf(v.y); o.z = f2bf(v.z); o.w = f2bf(v.w);
    *(ushort4*)&out[i] = o;
  }
}

// ---- concat biases: [bq*C2F | bk | bvd] -> bqkv[2560] ----------------------
__global__ __launch_bounds__(256) void bconcat(const float* __restrict__ bq,
                                               const float* __restrict__ bk,
                                               const float* __restrict__ bvd,
                                               float* __restrict__ o) {
  int i = blockIdx.x * 256 + threadIdx.x;
  if (i < NQKV) {
    float v = (i < 1024) ? bq[i] * C2F : (i < 2048 ? bk[i - 1024] : bvd[i - 2048]);
    o[i] = v;
  }
}

// ---- LayerNorm (optionally fused residual add + x2 passthrough) -----------
__global__ __launch_bounds__(256) void ln_kernel(const float* __restrict__ xin,
                                                 const float* __restrict__ addin,
                                                 const float* __restrict__ gam,
                                                 const float* __restrict__ bet,
                                                 u16* __restrict__ hout,
                                                 float* __restrict__ x2out) {
  int row = blockIdx.x, tid = threadIdx.x;
  size_t base = (size_t)row * D_ + tid * 4;
  float4 v = *(const float4*)&xin[base];
  if (addin) {
    float4 a = *(const float4*)&addin[base];
    v.x += a.x; v.y += a.y; v.z += a.z; v.w += a.w;
  }
  if (x2out) *(float4*)&x2out[base] = v;
  float s = v.x + v.y + v.z + v.w;
  float ss = v.x * v.x + v.y * v.y + v.z * v.z + v.w * v.w;
#pragma unroll
  for (int off = 32; off > 0; off >>= 1) {
    s += __shfl_down(s, off);
    ss += __shfl_down(ss, off);
  }
  __shared__ float red[8];
  int wv = tid >> 6;
  if ((tid & 63) == 0) { red[wv] = s; red[4 + wv] = ss; }
  __syncthreads();
  if (tid == 0) {
    float s1 = red[0] + red[1] + red[2] + red[3];
    float s2 = red[4] + red[5] + red[6] + red[7];
    float mu = s1 * (1.0f / D_);
    red[0] = mu;
    red[1] = s2 * (1.0f / D_) - mu * mu;
  }
  __syncthreads();
  float mu = red[0];
  float rstd = rsqrtf(red[1] + 1e-5f);
  int ci = tid * 4;
  ushort4 o;
  o.x = f2bf((v.x - mu) * rstd * gam[ci + 0] + bet[ci + 0]);
  o.y = f2bf((v.y - mu) * rstd * gam[ci + 1] + bet[ci + 1]);
  o.z = f2bf((v.z - mu) * rstd * gam[ci + 2] + bet[ci + 2]);
  o.w = f2bf((v.w - mu) * rstd * gam[ci + 3] + bet[ci + 3]);
  *(ushort4*)&hout[base] = o;
}

// ---- NT GEMM (128x128, 2-phase dbuf): used for the fused QKV projection ---
template <int MODE>
__global__ __launch_bounds__(256) void gemm_nt(const u16* __restrict__ A,
                                               const u16* __restrict__ Bt,
                                               int K, int lda, int ldb,
                                               const float* __restrict__ bias,
                                               const float* __restrict__ res,
                                               void* __restrict__ Cout,
                                               void* __restrict__ Cout2, int ldc) {
  __shared__ __align__(16) u16 As0[128 * 32];
  __shared__ __align__(16) u16 Bs0[128 * 32];
  __shared__ __align__(16) u16 As1[128 * 32];
  __shared__ __align__(16) u16 Bs1[128 * 32];
  int tid = threadIdx.x;
  int lane = tid & 63, wid = tid >> 6;
  int wm = wid >> 1, wn = wid & 1;
  int row0 = blockIdx.y * 128, col0 = blockIdx.x * 128;
  int l15 = lane & 15, g = lane >> 4;
  int srow = lane >> 2, scol = (lane & 3) * 8;
  f32x4 acc[4][4] = {};
  const u16* Ap = A + (size_t)row0 * lda;
  const u16* Bp = Bt + (size_t)col0 * ldb;

  auto STAGE = [&](u16* AS, u16* BS, int kk) {
#pragma unroll
    for (int i = 0; i < 2; ++i) {
      int c = wid * 2 + i;
      gload_lds16(Ap + (size_t)(c * 16 + srow) * lda + kk + scol, &AS[c * 512]);
      gload_lds16(Bp + (size_t)(c * 16 + srow) * ldb + kk + scol, &BS[c * 512]);
    }
  };
  auto COMPUTE = [&](const u16* AS, const u16* BS) {
    bf16x8 af[4], bfr[4];
#pragma unroll
    for (int t = 0; t < 4; ++t) {
      af[t] = *(const bf16x8*)&AS[(wm * 64 + t * 16 + l15) * 32 + g * 8];
      bfr[t] = *(const bf16x8*)&BS[(wn * 64 + t * 16 + l15) * 32 + g * 8];
    }
#pragma unroll
    for (int mt = 0; mt < 4; ++mt)
#pragma unroll
      for (int nt = 0; nt < 4; ++nt)
        acc[mt][nt] = __builtin_amdgcn_mfma_f32_16x16x32_bf16(af[mt], bfr[nt],
                                                              acc[mt][nt], 0, 0, 0);
  };

  STAGE(As0, Bs0, 0);
  __syncthreads();
  for (int k0 = 0; k0 < K; k0 += 64) {
    if (k0 + 32 < K) STAGE(As1, Bs1, k0 + 32);
    COMPUTE(As0, Bs0);
    __syncthreads();
    if (k0 + 64 < K) STAGE(As0, Bs0, k0 + 64);
    COMPUTE(As1, Bs1);
    __syncthreads();
  }

#pragma unroll
  for (int mt = 0; mt < 4; ++mt) {
#pragma unroll
    for (int nt = 0; nt < 4; ++nt) {
      int cc = col0 + wn * 64 + nt * 16 + l15;
      float bv = bias ? bias[cc] : 0.0f;
#pragma unroll
      for (int j = 0; j < 4; ++j) {
        int rr = row0 + wm * 64 + mt * 16 + g * 4 + j;
        float v = acc[mt][nt][j] + bv;
        if (MODE == 1) v = gelu_f(v);
        if (MODE == 2) {
          ((float*)Cout)[(size_t)rr * ldc + cc] = v + res[(size_t)rr * ldc + cc];
        } else {
          ((u16*)Cout)[(size_t)rr * ldc + cc] = f2bf(v);
        }
      }
    }
  }
  (void)Cout2;
}

// ---- gemm8: 256x256 deep-pipelined GEMM ------------------------------------
// 8 waves (2Mx4N), BK=64, dbuf 128KB dynamic LDS, XOR-swizzled rows.
// Per K-step: {ds_read kk0 | STAGE_A(next) | 32 MFMA | ds_read kk1 |
// STAGE_B(next) | 32 MFMA | vmcnt(0) | s_barrier}.
// MODE 1: bf16 gelu(v+bias) -> Cb. MODE 4: split-K, z=0 -> f32 raw to Cf,
// z=1..3 -> bf16 raw to P1/P2/P3.
template <int MODE>
__global__ __launch_bounds__(512, 2) void gemm8(
    const u16* __restrict__ A, const u16* __restrict__ Bt,
    int lda, int ldb, int nk,
    const float* __restrict__ bias,
    float* __restrict__ Cf, u16* __restrict__ Cb,
    u16* __restrict__ P1, u16* __restrict__ P2, u16* __restrict__ P3,
    int ldc) {
  extern __shared__ __align__(16) char smem[];
  int tid = threadIdx.x;
  int lane = tid & 63, wid = tid >> 6;
  int wm = wid >> 2, wn = wid & 3;
  int l15 = lane & 15, g = lane >> 4;
  int row0 = blockIdx.y * 256, col0 = blockIdx.x * 256;
  int koff = blockIdx.z * (nk * 64);
  const u16* Ap = A + (size_t)row0 * lda + koff;
  const u16* Bp = Bt + (size_t)col0 * ldb + koff;
  int trow = tid >> 3;                                  // 0..63
  int sbyte = ((tid & 7) * 16) ^ ((trow & 7) << 4);     // pre-swizzled src byte
  int xr = (l15 & 7) << 4;                              // read-side XOR

  f32x4 acc[8][4] = {};

  auto STAGE_A = [&](int buf, int kt) {
#pragma unroll
    for (int l = 0; l < 4; ++l)
      gload_lds16((const char*)(Ap + (size_t)(l * 64 + trow) * lda + kt) + sbyte,
                  smem + buf * 65536 + (l * 64 + wid * 8) * 128);
  };
  auto STAGE_B = [&](int buf, int kt) {
#pragma unroll
    for (int l = 0; l < 4; ++l)
      gload_lds16((const char*)(Bp + (size_t)(l * 64 + trow) * ldb + kt) + sbyte,
                  smem + buf * 65536 + 32768 + (l * 64 + wid * 8) * 128);
  };

  STAGE_A(0, 0);
  STAGE_B(0, 0);
  asm volatile("s_waitcnt vmcnt(0)" ::: "memory");
  __builtin_amdgcn_sched_barrier(0);
  __builtin_amdgcn_s_barrier();

  int cur = 0;
  for (int it = 0; it < nk; ++it) {
    const char* Ab = smem + cur * 65536 + (wm * 128 + l15) * 128;
    const char* Bb = smem + cur * 65536 + 32768 + (wn * 64 + l15) * 128;
    bool nxt = (it + 1 < nk);
#pragma unroll
    for (int kk = 0; kk < 2; ++kk) {
      int kq = (kk * 64 + g * 16) ^ xr;
      bf16x8 bfr[4], af[8];
#pragma unroll
      for (int nt = 0; nt < 4; ++nt)
        bfr[nt] = *(const bf16x8*)(Bb + nt * 2048 + kq);
#pragma unroll
      for (int mt = 0; mt < 8; ++mt)
        af[mt] = *(const bf16x8*)(Ab + mt * 2048 + kq);
      if (nxt) {
        if (kk == 0) STAGE_A(cur ^ 1, (it + 1) * 64);
        else         STAGE_B(cur ^ 1, (it + 1) * 64);
      }
      __builtin_amdgcn_s_setprio(1);
#pragma unroll
      for (int mt = 0; mt < 8; ++mt)
#pragma unroll
        for (int nt = 0; nt < 4; ++nt)
          acc[mt][nt] = __builtin_amdgcn_mfma_f32_16x16x32_bf16(af[mt], bfr[nt],
                                                                acc[mt][nt], 0, 0, 0);
      __builtin_amdgcn_s_setprio(0);
    }
    asm volatile("s_waitcnt vmcnt(0)" ::: "memory");  // this iter's 8 stage loads
    __builtin_amdgcn_sched_barrier(0);
    __builtin_amdgcn_s_barrier();  // all reads of cur retired; cur^1 ready
    cur ^= 1;
  }

  // epilogue: C/D layout col=lane&15, row=(lane>>4)*4+j
  u16* pp = (u16*)nullptr;
  if (MODE == 4 && blockIdx.z != 0)
    pp = (blockIdx.z == 1) ? P1 : (blockIdx.z == 2 ? P2 : P3);
#pragma unroll
  for (int mt = 0; mt < 8; ++mt) {
#pragma unroll
    for (int nt = 0; nt < 4; ++nt) {
      int cc = col0 + wn * 64 + nt * 16 + l15;
      float bv = (MODE == 1) ? bias[cc] : 0.0f;
#pragma unroll
      for (int j = 0; j < 4; ++j) {
        int rr = row0 + wm * 128 + mt * 16 + g * 4 + j;
        float v = acc[mt][nt][j] + bv;
        if (MODE == 1) {
          Cb[(size_t)rr * ldc + cc] = f2bf(gelu_f(v));
        } else {
          if (blockIdx.z == 0) Cf[(size_t)rr * ldc + cc] = v;
          else                 pp[(size_t)rr * ldc + cc] = f2bf(v);
        }
      }
    }
  }
}

// ---- split-K reduce: out += p1+p2+p3 (bf16) + b2[col] + x2 -----------------
__global__ __launch_bounds__(256) void reduce2(float* __restrict__ out,
                                               const u16* __restrict__ p1,
                                               const u16* __restrict__ p2,
                                               const u16* __restrict__ p3,
                                               const float* __restrict__ b2,
                                               const float* __restrict__ x2) {
  int i = (blockIdx.x * 256 + threadIdx.x) * 4;
  float4 o = *(float4*)&out[i];
  ushort4 a = *(const ushort4*)&p1[i];
  ushort4 b = *(const ushort4*)&p2[i];
  ushort4 c = *(const ushort4*)&p3[i];
  float4 r = *(const float4*)&x2[i];
  int cix = i & (D_ - 1);
  o.x += bf2f(a.x) + bf2f(b.x) + bf2f(c.x) + b2[cix + 0] + r.x;
  o.y += bf2f(a.y) + bf2f(b.y) + bf2f(c.y) + b2[cix + 1] + r.y;
  o.z += bf2f(a.z) + bf2f(b.z) + bf2f(c.z) + b2[cix + 2] + r.z;
  o.w += bf2f(a.w) + bf2f(b.w) + bf2f(c.w) + b2[cix + 3] + r.w;
  *(float4*)&out[i] = o;
}

// ---- low-rank V up-proj -> V^T [b,h][e][t] bf16 ----------------------------
__global__ __launch_bounds__(256) void vu_kernel(const u16* __restrict__ vd,
                                                 const u16* __restrict__ wvu,
                                                 const float* __restrict__ bvu,
                                                 u16* __restrict__ v_t) {
  int t0 = blockIdx.x * 64, h = blockIdx.y, b = blockIdx.z;
  __shared__ u16 vds[64][32];
  __shared__ u16 vt[64][65];
  int tid = threadIdx.x;
  {
    int rr2 = tid >> 2, c8 = (tid & 3) * 8;
    *(bf16x8*)&vds[rr2][c8] =
        *(const bf16x8*)&vd[(size_t)(b * S_ + t0 + rr2) * NQKV + 2048 + h * R_ + c8];
  }
  __syncthreads();
  int e = tid & 63, tg = (tid >> 6) * 16;
  float wcol[32];
#pragma unroll
  for (int r = 0; r < 32; ++r) wcol[r] = bf2f(wvu[((size_t)h * R_ + r) * HD_ + e]);
  float bb = bvu[h * HD_ + e];
  for (int i = 0; i < 16; ++i) {
    int t = tg + i;
    float acc = bb;
#pragma unroll
    for (int r = 0; r < 32; ++r) acc += bf2f(vds[t][r]) * wcol[r];
    vt[t][e] = f2bf(acc);
  }
  __syncthreads();
  for (int idx = tid; idx < 64 * 64; idx += 256) {
    int e2 = idx >> 6, t2 = idx & 63;
    v_t[((size_t)(b * H_ + h) * HD_ + e2) * S_ + t0 + t2] = vt[t2][e2];
  }
}

// ---- attention: reversed-causal (key t >= query s) -------------------------
__global__ __launch_bounds__(256) void attn_kernel(const u16* __restrict__ cqkv,
                                                   const u16* __restrict__ v_t,
                                                   float* __restrict__ o) {
  int tid = threadIdx.x;
  int lane = tid & 63, w = tid >> 6;
  int h = blockIdx.y, b = blockIdx.z;
  int r = lane & 15, g = lane >> 4;
  const u16* qp = cqkv + (size_t)(b * S_) * NQKV + h * HD_;
  const u16* kp = cqkv + (size_t)(b * S_) * NQKV + 1024 + h * HD_;
  const u16* vp = v_t + (size_t)(b * H_ + h) * HD_ * S_;

  __shared__ u16 Ks[2][64 * 64];
  __shared__ u16 Vs[2][64 * 64];
  __shared__ u16 Pl[4][16 * 64];
  u16* Pw = Pl[w];

  int srow = w * 16 + (lane >> 3);
  int ssw = ((lane & 7) * 16) ^ (((lane >> 3) & 7) << 4);

  int xr = (r & 7) << 4;
  int kq0 = ((g * 16) ^ xr) >> 1;
  int kq1 = ((64 + g * 16) ^ xr) >> 1;

  auto STAGE = [&](int buf, int kt) {
    gload_lds16((const char*)(kp + (size_t)(kt + srow) * NQKV) + ssw,
                &Ks[buf][w * 1024]);
    gload_lds16((const char*)(kp + (size_t)(kt + srow + 8) * NQKV) + ssw,
                &Ks[buf][w * 1024 + 512]);
    gload_lds16((const char*)(vp + (size_t)srow * S_ + kt) + ssw,
                &Vs[buf][w * 1024]);
    gload_lds16((const char*)(vp + (size_t)(srow + 8) * S_ + kt) + ssw,
                &Vs[buf][w * 1024 + 512]);
  };

#pragma unroll 1
  for (int half = 0; half < 2; ++half) {
    int qb = half ? (S_ - 64) - blockIdx.x * 64 : blockIdx.x * 64;
    int s0 = qb + w * 16;
    int qrow = s0 + r;

    bf16x8 aq0 = *(const bf16x8*)(qp + (size_t)(s0 + r) * NQKV + g * 8);
    bf16x8 aq1 = *(const bf16x8*)(qp + (size_t)(s0 + r) * NQKV + 32 + g * 8);

    f32x4 oa[4] = {};
    float m_ = -1e30f, l_ = 0.0f;

    STAGE(0, qb);
    __syncthreads();
    int cur = 0;
    for (int kt = qb; kt < S_; kt += 64) {
      if (kt + 64 < S_) STAGE(cur ^ 1, kt + 64);
      const u16* Kb = &Ks[cur][0];
      const u16* Vb = &Vs[cur][0];

      f32x4 sc[4] = {};
#pragma unroll
      for (int blk = 0; blk < 4; ++blk) {
        bf16x8 a0 = *(const bf16x8*)&Kb[((blk * 16 + r) << 6) + kq0];
        bf16x8 a1 = *(const bf16x8*)&Kb[((blk * 16 + r) << 6) + kq1];
        sc[blk] = __builtin_amdgcn_mfma_f32_16x16x32_bf16(a0, aq0, sc[blk], 0, 0, 0);
        sc[blk] = __builtin_amdgcn_mfma_f32_16x16x32_bf16(a1, aq1, sc[blk], 0, 0, 0);
      }

      float p[16];
      if (kt == qb) {
#pragma unroll
        for (int blk = 0; blk < 4; ++blk)
#pragma unroll
          for (int j = 0; j < 4; ++j) {
            int kk = kt + blk * 16 + g * 4 + j;
            p[blk * 4 + j] = (kk < qrow) ? -1e30f : sc[blk][j];
          }
      } else {
#pragma unroll
        for (int blk = 0; blk < 4; ++blk)
#pragma unroll
          for (int j = 0; j < 4; ++j) p[blk * 4 + j] = sc[blk][j];
      }
      float mx = p[0];
#pragma unroll
      for (int i = 1; i < 16; ++i) mx = fmaxf(mx, p[i]);
      mx = fmaxf(mx, __shfl_xor(mx, 16));
      mx = fmaxf(mx, __shfl_xor(mx, 32));
      float mn = fmaxf(m_, mx);
      float scl = __builtin_amdgcn_exp2f(m_ - mn);
      m_ = mn;
      float sm = 0.0f;
#pragma unroll
      for (int i = 0; i < 16; ++i) {
        p[i] = __builtin_amdgcn_exp2f(p[i] - mn);
        sm += p[i];
      }
      sm += __shfl_xor(sm, 16);
      sm += __shfl_xor(sm, 32);
      l_ = l_ * scl + sm;
#pragma unroll
      for (int et = 0; et < 4; ++et) oa[et] *= scl;

#pragma unroll
      for (int blk = 0; blk < 4; ++blk) {
        uint2 pk;
        pk.x = pk_bf16(p[blk * 4 + 0], p[blk * 4 + 1]);
        pk.y = pk_bf16(p[blk * 4 + 2], p[blk * 4 + 3]);
        *(uint2*)&Pw[(r << 6) + ((((blk << 5) + (g << 3)) ^ xr) >> 1)] = pk;
      }
      asm volatile("s_waitcnt lgkmcnt(0)" ::: "memory");
      bf16x8 pb0 = *(const bf16x8*)&Pw[(r << 6) + kq0];
      bf16x8 pb1 = *(const bf16x8*)&Pw[(r << 6) + kq1];
#pragma unroll
      for (int et = 0; et < 4; ++et) {
        bf16x8 v0 = *(const bf16x8*)&Vb[((et * 16 + r) << 6) + kq0];
        bf16x8 v1 = *(const bf16x8*)&Vb[((et * 16 + r) << 6) + kq1];
        oa[et] = __builtin_amdgcn_mfma_f32_16x16x32_bf16(v0, pb0, oa[et], 0, 0, 0);
        oa[et] = __builtin_amdgcn_mfma_f32_16x16x32_bf16(v1, pb1, oa[et], 0, 0, 0);
      }
      __syncthreads();
      cur ^= 1;
    }

    float inv = 1.0f / l_;
#pragma unroll
    for (int et = 0; et < 4; ++et)
#pragma unroll
      for (int j = 0; j < 4; ++j)
        o[(size_t)(b * S_ + s0 + r) * D_ + h * HD_ + et * 16 + g * 4 + j] =
            oa[et][j] * inv;
  }
}

// one-time (dlopen) LDS-limit raise for the 128KB-dynamic-shared kernels
namespace {
struct GemmAttrInit {
  GemmAttrInit() {
    hipFuncSetAttribute((const void*)gemm8<1>,
                        hipFuncAttributeMaxDynamicSharedMemorySize, 131072);
    hipFuncSetAttribute((const void*)gemm8<4>,
                        hipFuncAttributeMaxDynamicSharedMemorySize, 131072);
  }
};
GemmAttrInit _gemm_attr_init;
}  // namespace

extern "C" void kernel_launch(void* const* d_in, const int* in_sizes, int n_in,
                              void* d_out, int out_size, void* d_ws, size_t ws_size,
                              hipStream_t stream) {
  const float* x = (const float*)d_in[0];
  const float* ln1_g = (const float*)d_in[1];
  const float* ln1_b = (const float*)d_in[2];
  const float* Wq = (const float*)d_in[3];
  const float* bq = (const float*)d_in[4];
  const float* Wk = (const float*)d_in[5];
  const float* bk = (const float*)d_in[6];
  const float* Wvd = (const float*)d_in[7];
  const float* bvd = (const float*)d_in[8];
  const float* Wvu = (const float*)d_in[9];
  const float* bvu = (const float*)d_in[10];
  const float* ln2_g = (const float*)d_in[11];
  const float* ln2_b = (const float*)d_in[12];
  const float* W1 = (const float*)d_in[13];
  const float* b1 = (const float*)d_in[14];
  const float* W2 = (const float*)d_in[15];
  const float* b2 = (const float*)d_in[16];
  float* out = (float*)d_out;
  (void)in_sizes; (void)n_in; (void)out_size; (void)ws_size;

  char* ws = (char*)d_ws;
  const size_t MB = 1024 * 1024;
  const size_t KB = 1024;
  u16* wqkvT = (u16*)(ws + 0);                    // [2560x1024] bf16, 5 MB
  u16* wvuB = (u16*)(ws + 5 * MB);                // 64 KB
  float* bqkv = (float*)(ws + 5 * MB + 64 * KB);  // 10 KB
  u16* w1T = (u16*)(ws + 5 * MB + 384 * KB);      // 8 MB -> 13.375
  u16* w2T = (u16*)(ws + 13 * MB + 384 * KB);     // 8 MB -> 21.375
  u16* hbuf = (u16*)(ws + 21 * MB + 384 * KB);    // 8 MB -> 29.375
  u16* cqkv = (u16*)(ws + 29 * MB + 384 * KB);    // 20 MB -> 49.375
  u16* vT = (u16*)(ws + 49 * MB + 384 * KB);      // 8 MB -> 57.375
  float* ob = (float*)(ws + 57 * MB + 384 * KB);  // 16 MB -> 73.375
  float* x2 = (float*)(ws + 73 * MB + 384 * KB);  // 16 MB -> 89.375
  // lifetime-disjoint reuses:
  u16* ubuf = cqkv;            // 32 MB (cqkv+vT+ob[0:4MB]), dead by FFN1
  u16* p1 = (u16*)(ws + 0);    // 8 MB over wqkvT+..., dead by FFN2
  u16* p2 = (u16*)hbuf;        // 8 MB, hbuf dead after FFN1
  u16* p3 = (u16*)vT;          // 8 MB, vT dead after attention

  dim3 blk(256);
  wtrans<<<dim3(2, 32, 16), blk, 0, stream>>>(Wq, wqkvT, 1024, 64, 65536L, 65536L, C2F);
  wtrans<<<dim3(2, 32, 16), blk, 0, stream>>>(Wk, wqkvT + 1024 * 1024, 1024, 64,
                                              65536L, 65536L, 1.0f);
  wtrans<<<dim3(1, 32, 16), blk, 0, stream>>>(Wvd, wqkvT + 2048 * 1024, 1024, 32,
                                              32768L, 32768L, 1.0f);
  wconv<<<dim3(32), blk, 0, stream>>>(Wvu, wvuB, H_ * R_ * HD_);
  bconcat<<<dim3(10), blk, 0, stream>>>(bq, bk, bvd, bqkv);
  wtrans<<<dim3(128, 32, 1), blk, 0, stream>>>(W1, w1T, 1024, 4096, 0L, 0L, 1.0f);
  wtrans<<<dim3(32, 128, 1), blk, 0, stream>>>(W2, w2T, 4096, 1024, 0L, 0L, 1.0f);
  ln_kernel<<<dim3(M_), blk, 0, stream>>>(x, (const float*)nullptr, ln1_g, ln1_b,
                                          hbuf, (float*)nullptr);
  // fused QKV projection (2-phase 128² — 640 blocks, 2.5/CU)
  gemm_nt<0><<<dim3(20, 32), blk, 0, stream>>>(hbuf, wqkvT, 1024, 1024, 1024, bqkv,
                                               (const float*)nullptr, (void*)cqkv,
                                               (void*)nullptr, NQKV);
  vu_kernel<<<dim3(S_ / 64, H_, B_), blk, 0, stream>>>(cqkv, wvuB, bvu, vT);
  attn_kernel<<<dim3(S_ / 128, H_, B_), blk, 0, stream>>>(cqkv, vT, ob);
  ln_kernel<<<dim3(M_), blk, 0, stream>>>(x, ob, ln2_g, ln2_b, hbuf, x2);
  // FFN1: 256² deep pipeline, grid 16x16 = 1 block/CU
  gemm8<1><<<dim3(16, 16, 1), dim3(512), 131072, stream>>>(
      hbuf, w1T, 1024, 1024, 16, b1, (float*)nullptr, ubuf,
      (u16*)nullptr, (u16*)nullptr, (u16*)nullptr, 4096);
  // FFN2: 256² split-K=4, grid 4x16x4; z=0 -> f32 into out, z>0 -> bf16 partials
  gemm8<4><<<dim3(4, 16, 4), dim3(512), 131072, stream>>>(
      ubuf, w2T, 4096, 4096, 16, (const float*)nullptr, out, (u16*)nullptr,
      p1, p2, p3, 1024);
  // out += p1+p2+p3 + b2 + x2
  reduce2<<<dim3(M_ * D_ / 1024), blk, 0, stream>>>(out, p1, p2, p3, b2, x2);
}

// Round 8
// 232.420 us; speedup vs baseline: 2.2696x; 1.0394x over previous
//
#include <hip/hip_runtime.h>

// ---------------------------------------------------------------------------
// TransformerBlock: LN1 -> QKV proj (fused) -> reversed-causal attention
// (scale 1/sqrt(D)=1/32) -> residual -> LN2 -> GELU FFN -> residual.
// B=2 S=2048 D=1024 H=16 HD=64 R=32 F=4096. All d_in/d_out fp32; internal
// compute bf16 MFMA.
// R7: attention v4 —
//   * 8-wave blocks, QBLK=128 triangle-paired (34 uniform steps, 256 blocks
//     = 1/CU; per-CU steps halved vs R6)
//   * counted-vmcnt 3-buffer ring: vmcnt(2) + ONE s_barrier per step, stage
//     issued post-barrier; no vmcnt(0) drain in loop. Q staged via LDS so
//     no compiler vmcnt waits mix into the counted ladder.
//   * grid (H,B,8): all 8 q-blocks of a (b,h) share one XCD's L2 for K/V.
// ---------------------------------------------------------------------------

typedef unsigned short u16;
typedef __attribute__((ext_vector_type(4))) float f32x4;
typedef __attribute__((ext_vector_type(8))) __bf16 bf16x8;

#define B_ 2
#define S_ 2048
#define D_ 1024
#define H_ 16
#define HD_ 64
#define R_ 32
#define F_ 4096
#define M_ (B_ * S_)   // 4096 rows
#define NQKV 2560      // 1024 q + 1024 k + 512 vd
// (1/sqrt(D)) * log2(e): folded into Wq/bq so QK^T scores are exp2-ready
#define C2F 0.04508422002778011f

__device__ __forceinline__ u16 f2bf(float f) {
  union { float f; unsigned u; } v; v.f = f;
  unsigned u = v.u;
  return (u16)((u + 0x7FFFu + ((u >> 16) & 1u)) >> 16);  // RNE
}
__device__ __forceinline__ float bf2f(u16 h) {
  union { unsigned u; float f; } v; v.u = ((unsigned)h) << 16;
  return v.f;
}
__device__ __forceinline__ unsigned pk_bf16(float lo, float hi) {
  unsigned r;
  asm volatile("v_cvt_pk_bf16_f32 %0, %1, %2" : "=v"(r) : "v"(lo), "v"(hi));
  return r;
}

typedef __attribute__((address_space(1))) void gvoid;
typedef __attribute__((address_space(3))) void lvoid;
// async global->LDS, 16B/lane; lds base must be wave-uniform (lane*16 implicit)
__device__ __forceinline__ void gload_lds16(const void* g, void* l) {
  __builtin_amdgcn_global_load_lds((gvoid*)(void*)g, (lvoid*)l, 16, 0, 0);
}

__device__ __forceinline__ float gelu_f(float x) {
  float t = tanhf(0.7978845608028654f * (x + 0.044715f * x * x * x));
  return 0.5f * x * (1.0f + t);
}

// ---- fp32 [Rr,Cc] (batched) -> bf16 transposed [Cc,Rr], optional scale ----
__global__ __launch_bounds__(256) void wtrans(const float* __restrict__ in,
                                              u16* __restrict__ out,
                                              int Rr, int Cc, long ibs, long obs,
                                              float scale) {
  __shared__ float tile[32][33];
  const float* ip = in + (size_t)blockIdx.z * ibs;
  u16* op = out + (size_t)blockIdx.z * obs;
  int c0 = blockIdx.x * 32, r0 = blockIdx.y * 32;
  int tx = threadIdx.x & 31, ty = threadIdx.x >> 5;  // 32 x 8
#pragma unroll
  for (int j = 0; j < 32; j += 8)
    tile[ty + j][tx] = ip[(size_t)(r0 + ty + j) * Cc + c0 + tx];
  __syncthreads();
#pragma unroll
  for (int j = 0; j < 32; j += 8)
    op[(size_t)(c0 + ty + j) * Rr + r0 + tx] = f2bf(tile[tx][ty + j] * scale);
}

// ---- flat fp32 -> bf16 -----------------------------------------------------
__global__ __launch_bounds__(256) void wconv(const float* __restrict__ in,
                                             u16* __restrict__ out, int n) {
  int i = (blockIdx.x * 256 + threadIdx.x) * 4;
  if (i < n) {
    float4 v = *(const float4*)&in[i];
    ushort4 o;
    o.x = f2bf(v.x); o.y = f2bf(v.y); o.z = f2bf(v.z); o.w = f2bf(v.w);
    *(ushort4*)&out[i] = o;
  }
}

// ---- concat biases: [bq*C2F | bk | bvd] -> bqkv[2560] ----------------------
__global__ __launch_bounds__(256) void bconcat(const float* __restrict__ bq,
                                               const float* __restrict__ bk,
                                               const float* __restrict__ bvd,
                                               float* __restrict__ o) {
  int i = blockIdx.x * 256 + threadIdx.x;
  if (i < NQKV) {
    float v = (i < 1024) ? bq[i] * C2F : (i < 2048 ? bk[i - 1024] : bvd[i - 2048]);
    o[i] = v;
  }
}

// ---- LayerNorm (optionally fused residual add + x2 passthrough) -----------
__global__ __launch_bounds__(256) void ln_kernel(const float* __restrict__ xin,
                                                 const float* __restrict__ addin,
                                                 const float* __restrict__ gam,
                                                 const float* __restrict__ bet,
                                                 u16* __restrict__ hout,
                                                 float* __restrict__ x2out) {
  int row = blockIdx.x, tid = threadIdx.x;
  size_t base = (size_t)row * D_ + tid * 4;
  float4 v = *(const float4*)&xin[base];
  if (addin) {
    float4 a = *(const float4*)&addin[base];
    v.x += a.x; v.y += a.y; v.z += a.z; v.w += a.w;
  }
  if (x2out) *(float4*)&x2out[base] = v;
  float s = v.x + v.y + v.z + v.w;
  float ss = v.x * v.x + v.y * v.y + v.z * v.z + v.w * v.w;
#pragma unroll
  for (int off = 32; off > 0; off >>= 1) {
    s += __shfl_down(s, off);
    ss += __shfl_down(ss, off);
  }
  __shared__ float red[8];
  int wv = tid >> 6;
  if ((tid & 63) == 0) { red[wv] = s; red[4 + wv] = ss; }
  __syncthreads();
  if (tid == 0) {
    float s1 = red[0] + red[1] + red[2] + red[3];
    float s2 = red[4] + red[5] + red[6] + red[7];
    float mu = s1 * (1.0f / D_);
    red[0] = mu;
    red[1] = s2 * (1.0f / D_) - mu * mu;
  }
  __syncthreads();
  float mu = red[0];
  float rstd = rsqrtf(red[1] + 1e-5f);
  int ci = tid * 4;
  ushort4 o;
  o.x = f2bf((v.x - mu) * rstd * gam[ci + 0] + bet[ci + 0]);
  o.y = f2bf((v.y - mu) * rstd * gam[ci + 1] + bet[ci + 1]);
  o.z = f2bf((v.z - mu) * rstd * gam[ci + 2] + bet[ci + 2]);
  o.w = f2bf((v.w - mu) * rstd * gam[ci + 3] + bet[ci + 3]);
  *(ushort4*)&hout[base] = o;
}

// ---- NT GEMM (128x128, 2-phase dbuf): used for the fused QKV projection ---
template <int MODE>
__global__ __launch_bounds__(256) void gemm_nt(const u16* __restrict__ A,
                                               const u16* __restrict__ Bt,
                                               int K, int lda, int ldb,
                                               const float* __restrict__ bias,
                                               const float* __restrict__ res,
                                               void* __restrict__ Cout,
                                               void* __restrict__ Cout2, int ldc) {
  __shared__ __align__(16) u16 As0[128 * 32];
  __shared__ __align__(16) u16 Bs0[128 * 32];
  __shared__ __align__(16) u16 As1[128 * 32];
  __shared__ __align__(16) u16 Bs1[128 * 32];
  int tid = threadIdx.x;
  int lane = tid & 63, wid = tid >> 6;
  int wm = wid >> 1, wn = wid & 1;
  int row0 = blockIdx.y * 128, col0 = blockIdx.x * 128;
  int l15 = lane & 15, g = lane >> 4;
  int srow = lane >> 2, scol = (lane & 3) * 8;
  f32x4 acc[4][4] = {};
  const u16* Ap = A + (size_t)row0 * lda;
  const u16* Bp = Bt + (size_t)col0 * ldb;

  auto STAGE = [&](u16* AS, u16* BS, int kk) {
#pragma unroll
    for (int i = 0; i < 2; ++i) {
      int c = wid * 2 + i;
      gload_lds16(Ap + (size_t)(c * 16 + srow) * lda + kk + scol, &AS[c * 512]);
      gload_lds16(Bp + (size_t)(c * 16 + srow) * ldb + kk + scol, &BS[c * 512]);
    }
  };
  auto COMPUTE = [&](const u16* AS, const u16* BS) {
    bf16x8 af[4], bfr[4];
#pragma unroll
    for (int t = 0; t < 4; ++t) {
      af[t] = *(const bf16x8*)&AS[(wm * 64 + t * 16 + l15) * 32 + g * 8];
      bfr[t] = *(const bf16x8*)&BS[(wn * 64 + t * 16 + l15) * 32 + g * 8];
    }
#pragma unroll
    for (int mt = 0; mt < 4; ++mt)
#pragma unroll
      for (int nt = 0; nt < 4; ++nt)
        acc[mt][nt] = __builtin_amdgcn_mfma_f32_16x16x32_bf16(af[mt], bfr[nt],
                                                              acc[mt][nt], 0, 0, 0);
  };

  STAGE(As0, Bs0, 0);
  __syncthreads();
  for (int k0 = 0; k0 < K; k0 += 64) {
    if (k0 + 32 < K) STAGE(As1, Bs1, k0 + 32);
    COMPUTE(As0, Bs0);
    __syncthreads();
    if (k0 + 64 < K) STAGE(As0, Bs0, k0 + 64);
    COMPUTE(As1, Bs1);
    __syncthreads();
  }

#pragma unroll
  for (int mt = 0; mt < 4; ++mt) {
#pragma unroll
    for (int nt = 0; nt < 4; ++nt) {
      int cc = col0 + wn * 64 + nt * 16 + l15;
      float bv = bias ? bias[cc] : 0.0f;
#pragma unroll
      for (int j = 0; j < 4; ++j) {
        int rr = row0 + wm * 64 + mt * 16 + g * 4 + j;
        float v = acc[mt][nt][j] + bv;
        if (MODE == 1) v = gelu_f(v);
        if (MODE == 2) {
          ((float*)Cout)[(size_t)rr * ldc + cc] = v + res[(size_t)rr * ldc + cc];
        } else {
          ((u16*)Cout)[(size_t)rr * ldc + cc] = f2bf(v);
        }
      }
    }
  }
  (void)Cout2;
}

// ---- gemm8: 256x256 deep-pipelined GEMM ------------------------------------
template <int MODE>
__global__ __launch_bounds__(512, 2) void gemm8(
    const u16* __restrict__ A, const u16* __restrict__ Bt,
    int lda, int ldb, int nk,
    const float* __restrict__ bias,
    float* __restrict__ Cf, u16* __restrict__ Cb,
    u16* __restrict__ P1, u16* __restrict__ P2, u16* __restrict__ P3,
    int ldc) {
  extern __shared__ __align__(16) char smem[];
  int tid = threadIdx.x;
  int lane = tid & 63, wid = tid >> 6;
  int wm = wid >> 2, wn = wid & 3;
  int l15 = lane & 15, g = lane >> 4;
  int row0 = blockIdx.y * 256, col0 = blockIdx.x * 256;
  int koff = blockIdx.z * (nk * 64);
  const u16* Ap = A + (size_t)row0 * lda + koff;
  const u16* Bp = Bt + (size_t)col0 * ldb + koff;
  int trow = tid >> 3;
  int sbyte = ((tid & 7) * 16) ^ ((trow & 7) << 4);
  int xr = (l15 & 7) << 4;

  f32x4 acc[8][4] = {};

  auto STAGE_A = [&](int buf, int kt) {
#pragma unroll
    for (int l = 0; l < 4; ++l)
      gload_lds16((const char*)(Ap + (size_t)(l * 64 + trow) * lda + kt) + sbyte,
                  smem + buf * 65536 + (l * 64 + wid * 8) * 128);
  };
  auto STAGE_B = [&](int buf, int kt) {
#pragma unroll
    for (int l = 0; l < 4; ++l)
      gload_lds16((const char*)(Bp + (size_t)(l * 64 + trow) * ldb + kt) + sbyte,
                  smem + buf * 65536 + 32768 + (l * 64 + wid * 8) * 128);
  };

  STAGE_A(0, 0);
  STAGE_B(0, 0);
  asm volatile("s_waitcnt vmcnt(0)" ::: "memory");
  __builtin_amdgcn_sched_barrier(0);
  __builtin_amdgcn_s_barrier();

  int cur = 0;
  for (int it = 0; it < nk; ++it) {
    const char* Ab = smem + cur * 65536 + (wm * 128 + l15) * 128;
    const char* Bb = smem + cur * 65536 + 32768 + (wn * 64 + l15) * 128;
    bool nxt = (it + 1 < nk);
#pragma unroll
    for (int kk = 0; kk < 2; ++kk) {
      int kq = (kk * 64 + g * 16) ^ xr;
      bf16x8 bfr[4], af[8];
#pragma unroll
      for (int nt = 0; nt < 4; ++nt)
        bfr[nt] = *(const bf16x8*)(Bb + nt * 2048 + kq);
#pragma unroll
      for (int mt = 0; mt < 8; ++mt)
        af[mt] = *(const bf16x8*)(Ab + mt * 2048 + kq);
      if (nxt) {
        if (kk == 0) STAGE_A(cur ^ 1, (it + 1) * 64);
        else         STAGE_B(cur ^ 1, (it + 1) * 64);
      }
      __builtin_amdgcn_s_setprio(1);
#pragma unroll
      for (int mt = 0; mt < 8; ++mt)
#pragma unroll
        for (int nt = 0; nt < 4; ++nt)
          acc[mt][nt] = __builtin_amdgcn_mfma_f32_16x16x32_bf16(af[mt], bfr[nt],
                                                                acc[mt][nt], 0, 0, 0);
      __builtin_amdgcn_s_setprio(0);
    }
    asm volatile("s_waitcnt vmcnt(0)" ::: "memory");
    __builtin_amdgcn_sched_barrier(0);
    __builtin_amdgcn_s_barrier();
    cur ^= 1;
  }

  u16* pp = (u16*)nullptr;
  if (MODE == 4 && blockIdx.z != 0)
    pp = (blockIdx.z == 1) ? P1 : (blockIdx.z == 2 ? P2 : P3);
#pragma unroll
  for (int mt = 0; mt < 8; ++mt) {
#pragma unroll
    for (int nt = 0; nt < 4; ++nt) {
      int cc = col0 + wn * 64 + nt * 16 + l15;
      float bv = (MODE == 1) ? bias[cc] : 0.0f;
#pragma unroll
      for (int j = 0; j < 4; ++j) {
        int rr = row0 + wm * 128 + mt * 16 + g * 4 + j;
        float v = acc[mt][nt][j] + bv;
        if (MODE == 1) {
          Cb[(size_t)rr * ldc + cc] = f2bf(gelu_f(v));
        } else {
          if (blockIdx.z == 0) Cf[(size_t)rr * ldc + cc] = v;
          else                 pp[(size_t)rr * ldc + cc] = f2bf(v);
        }
      }
    }
  }
}

// ---- split-K reduce: out += p1+p2+p3 (bf16) + b2[col] + x2 -----------------
__global__ __launch_bounds__(256) void reduce2(float* __restrict__ out,
                                               const u16* __restrict__ p1,
                                               const u16* __restrict__ p2,
                                               const u16* __restrict__ p3,
                                               const float* __restrict__ b2,
                                               const float* __restrict__ x2) {
  int i = (blockIdx.x * 256 + threadIdx.x) * 4;
  float4 o = *(float4*)&out[i];
  ushort4 a = *(const ushort4*)&p1[i];
  ushort4 b = *(const ushort4*)&p2[i];
  ushort4 c = *(const ushort4*)&p3[i];
  float4 r = *(const float4*)&x2[i];
  int cix = i & (D_ - 1);
  o.x += bf2f(a.x) + bf2f(b.x) + bf2f(c.x) + b2[cix + 0] + r.x;
  o.y += bf2f(a.y) + bf2f(b.y) + bf2f(c.y) + b2[cix + 1] + r.y;
  o.z += bf2f(a.z) + bf2f(b.z) + bf2f(c.z) + b2[cix + 2] + r.z;
  o.w += bf2f(a.w) + bf2f(b.w) + bf2f(c.w) + b2[cix + 3] + r.w;
  *(float4*)&out[i] = o;
}

// ---- low-rank V up-proj -> V^T [b,h][e][t] bf16 ----------------------------
__global__ __launch_bounds__(256) void vu_kernel(const u16* __restrict__ vd,
                                                 const u16* __restrict__ wvu,
                                                 const float* __restrict__ bvu,
                                                 u16* __restrict__ v_t) {
  int t0 = blockIdx.x * 64, h = blockIdx.y, b = blockIdx.z;
  __shared__ u16 vds[64][32];
  __shared__ u16 vt[64][65];
  int tid = threadIdx.x;
  {
    int rr2 = tid >> 2, c8 = (tid & 3) * 8;
    *(bf16x8*)&vds[rr2][c8] =
        *(const bf16x8*)&vd[(size_t)(b * S_ + t0 + rr2) * NQKV + 2048 + h * R_ + c8];
  }
  __syncthreads();
  int e = tid & 63, tg = (tid >> 6) * 16;
  float wcol[32];
#pragma unroll
  for (int r = 0; r < 32; ++r) wcol[r] = bf2f(wvu[((size_t)h * R_ + r) * HD_ + e]);
  float bb = bvu[h * HD_ + e];
  for (int i = 0; i < 16; ++i) {
    int t = tg + i;
    float acc = bb;
#pragma unroll
    for (int r = 0; r < 32; ++r) acc += bf2f(vds[t][r]) * wcol[r];
    vt[t][e] = f2bf(acc);
  }
  __syncthreads();
  for (int idx = tid; idx < 64 * 64; idx += 256) {
    int e2 = idx >> 6, t2 = idx & 63;
    v_t[((size_t)(b * H_ + h) * HD_ + e2) * S_ + t0 + t2] = vt[t2][e2];
  }
}

// ---- attention v4: reversed-causal (key t >= query s) ----------------------
// grid (H, B, 8) — all 8 q-blocks of a (b,h) share one XCD's L2.
// 8 waves, QBLK=128 (wave w owns 16 queries), triangle-paired q-tiles
// (bx*128 and 1920-128*bx -> uniform 34 steps). Counted-vmcnt 3-buffer ring:
// one s_barrier + vmcnt(2) per step (vmcnt(0) last), STAGE(it+2) after the
// barrier. Q staged via LDS (keeps compiler vmcnt waits out of the loop).
__global__ __launch_bounds__(512, 2) void attn_kernel(const u16* __restrict__ cqkv,
                                                      const u16* __restrict__ v_t,
                                                      float* __restrict__ o) {
  extern __shared__ __align__(16) u16 kv[];  // 3 bufs x (K 4096 + V 4096) u16
  __shared__ u16 Pl[8][16 * 64];             // per-wave Q then P^T tile
  int tid = threadIdx.x;
  int lane = tid & 63, w = tid >> 6;
  int h = blockIdx.x, b = blockIdx.y;
  int bx = blockIdx.z;
  int r = lane & 15, g = lane >> 4;
  const u16* qp = cqkv + (size_t)(b * S_) * NQKV + h * HD_;
  const u16* kp = cqkv + (size_t)(b * S_) * NQKV + 1024 + h * HD_;
  const u16* vp = v_t + (size_t)(b * H_ + h) * HD_ * S_;
  u16* Pw = Pl[w];

  // staging: wave w owns 8 rows of the 64-row K (and V) tile
  int srow = w * 8 + (lane >> 3);
  int ssw = ((lane & 7) * 16) ^ (((lane >> 3) & 7) << 4);  // pre-swz byte in row

  int xr = (r & 7) << 4;                // read-side XOR (rows = ..*16 + r)
  int kq0 = ((g * 16) ^ xr) >> 1;       // elem offset, k-group 0
  int kq1 = ((64 + g * 16) ^ xr) >> 1;  // elem offset, k-group 1

  auto STAGE = [&](int buf, int kt) {
    u16* base = kv + buf * 8192;
    gload_lds16((const char*)(kp + (size_t)(kt + srow) * NQKV) + ssw,
                base + w * 512);
    gload_lds16((const char*)(vp + (size_t)srow * S_ + kt) + ssw,
                base + 4096 + w * 512);
  };

#pragma unroll 1
  for (int half = 0; half < 2; ++half) {
    int qb = half ? (S_ - 128) - bx * 128 : bx * 128;
    int s0 = qb + w * 16;
    int qrow = s0 + r;

    // --- Q -> LDS (own wave area) -> regs; drains all prior vm ops ---------
    gload_lds16((const char*)(qp + (size_t)(s0 + (lane >> 3)) * NQKV) + ssw, Pw);
    gload_lds16((const char*)(qp + (size_t)(s0 + 8 + (lane >> 3)) * NQKV) + ssw,
                Pw + 512);
    asm volatile("s_waitcnt vmcnt(0)" ::: "memory");
    __builtin_amdgcn_sched_barrier(0);
    __builtin_amdgcn_s_barrier();  // all waves done previous half / Q staged
    __builtin_amdgcn_sched_barrier(0);
    bf16x8 aq0 = *(const bf16x8*)&Pw[(r << 6) + kq0];
    bf16x8 aq1 = *(const bf16x8*)&Pw[(r << 6) + kq1];

    f32x4 oa[4] = {};              // O^T: row e = et*16 + g*4+j, col q = r
    float m_ = -1e30f, l_ = 0.0f;  // per-lane online softmax state (exp2 dom)

    int nt = (S_ - qb) >> 6;
    STAGE(0, qb);
    STAGE(1, qb + 64);  // nt >= 2 always (min at half2 bx=0: nt=2)

    for (int it = 0; it < nt; ++it) {
      int kt = qb + it * 64;
      // wait own stage loads for step it (t_{it+1} may stay in flight)
      if (it + 1 < nt) {
        asm volatile("s_waitcnt vmcnt(2)" ::: "memory");
      } else {
        asm volatile("s_waitcnt vmcnt(0)" ::: "memory");
      }
      __builtin_amdgcn_sched_barrier(0);
      __builtin_amdgcn_s_barrier();  // all waves' loads for step it landed
      __builtin_amdgcn_sched_barrier(0);
      if (it + 2 < nt) STAGE((it + 2) % 3, qb + (it + 2) * 64);

      if (kt + 64 > s0) {  // wave-uniform; skip fully-masked steps
        const u16* Kb = kv + (it % 3) * 8192;
        const u16* Vb = Kb + 4096;

        f32x4 sc[4] = {};
#pragma unroll
        for (int blk = 0; blk < 4; ++blk) {
          bf16x8 a0 = *(const bf16x8*)&Kb[((blk * 16 + r) << 6) + kq0];
          bf16x8 a1 = *(const bf16x8*)&Kb[((blk * 16 + r) << 6) + kq1];
          sc[blk] = __builtin_amdgcn_mfma_f32_16x16x32_bf16(a0, aq0, sc[blk], 0, 0, 0);
          sc[blk] = __builtin_amdgcn_mfma_f32_16x16x32_bf16(a1, aq1, sc[blk], 0, 0, 0);
        }

        float p[16];
        if ((qrow & ~63) == kt) {  // diagonal step (wave-uniform)
#pragma unroll
          for (int blk = 0; blk < 4; ++blk)
#pragma unroll
            for (int j = 0; j < 4; ++j) {
              int kk = kt + blk * 16 + g * 4 + j;
              p[blk * 4 + j] = (kk < qrow) ? -1e30f : sc[blk][j];
            }
        } else {
#pragma unroll
          for (int blk = 0; blk < 4; ++blk)
#pragma unroll
            for (int j = 0; j < 4; ++j) p[blk * 4 + j] = sc[blk][j];
        }
        float mx = p[0];
#pragma unroll
        for (int i = 1; i < 16; ++i) mx = fmaxf(mx, p[i]);
        mx = fmaxf(mx, __shfl_xor(mx, 16));
        mx = fmaxf(mx, __shfl_xor(mx, 32));
        float mn = fmaxf(m_, mx);
        float scl = __builtin_amdgcn_exp2f(m_ - mn);
        m_ = mn;
        float sm = 0.0f;
#pragma unroll
        for (int i = 0; i < 16; ++i) {
          p[i] = __builtin_amdgcn_exp2f(p[i] - mn);
          sm += p[i];
        }
        sm += __shfl_xor(sm, 16);
        sm += __shfl_xor(sm, 32);
        l_ = l_ * scl + sm;
#pragma unroll
        for (int et = 0; et < 4; ++et) oa[et] *= scl;

        // P -> per-wave LDS (bf16, swizzled), read back as PV B-frags
#pragma unroll
        for (int blk = 0; blk < 4; ++blk) {
          uint2 pk;
          pk.x = pk_bf16(p[blk * 4 + 0], p[blk * 4 + 1]);
          pk.y = pk_bf16(p[blk * 4 + 2], p[blk * 4 + 3]);
          *(uint2*)&Pw[(r << 6) + ((((blk << 5) + (g << 3)) ^ xr) >> 1)] = pk;
        }
        asm volatile("s_waitcnt lgkmcnt(0)" ::: "memory");
        __builtin_amdgcn_sched_barrier(0);
        bf16x8 pb0 = *(const bf16x8*)&Pw[(r << 6) + kq0];
        bf16x8 pb1 = *(const bf16x8*)&Pw[(r << 6) + kq1];
#pragma unroll
        for (int et = 0; et < 4; ++et) {
          bf16x8 v0 = *(const bf16x8*)&Vb[((et * 16 + r) << 6) + kq0];
          bf16x8 v1 = *(const bf16x8*)&Vb[((et * 16 + r) << 6) + kq1];
          oa[et] = __builtin_amdgcn_mfma_f32_16x16x32_bf16(v0, pb0, oa[et], 0, 0, 0);
          oa[et] = __builtin_amdgcn_mfma_f32_16x16x32_bf16(v1, pb1, oa[et], 0, 0, 0);
        }
      }
    }

    float inv = 1.0f / l_;
#pragma unroll
    for (int et = 0; et < 4; ++et)
#pragma unroll
      for (int j = 0; j < 4; ++j)
        o[(size_t)(b * S_ + s0 + r) * D_ + h * HD_ + et * 16 + g * 4 + j] =
            oa[et][j] * inv;
  }
}

// one-time (dlopen) LDS-limit raise for dynamic-shared kernels
namespace {
struct GemmAttrInit {
  GemmAttrInit() {
    hipFuncSetAttribute((const void*)gemm8<1>,
                        hipFuncAttributeMaxDynamicSharedMemorySize, 131072);
    hipFuncSetAttribute((const void*)gemm8<4>,
                        hipFuncAttributeMaxDynamicSharedMemorySize, 131072);
    hipFuncSetAttribute((const void*)attn_kernel,
                        hipFuncAttributeMaxDynamicSharedMemorySize, 49152);
  }
};
GemmAttrInit _gemm_attr_init;
}  // namespace

extern "C" void kernel_launch(void* const* d_in, const int* in_sizes, int n_in,
                              void* d_out, int out_size, void* d_ws, size_t ws_size,
                              hipStream_t stream) {
  const float* x = (const float*)d_in[0];
  const float* ln1_g = (const float*)d_in[1];
  const float* ln1_b = (const float*)d_in[2];
  const float* Wq = (const float*)d_in[3];
  const float* bq = (const float*)d_in[4];
  const float* Wk = (const float*)d_in[5];
  const float* bk = (const float*)d_in[6];
  const float* Wvd = (const float*)d_in[7];
  const float* bvd = (const float*)d_in[8];
  const float* Wvu = (const float*)d_in[9];
  const float* bvu = (const float*)d_in[10];
  const float* ln2_g = (const float*)d_in[11];
  const float* ln2_b = (const float*)d_in[12];
  const float* W1 = (const float*)d_in[13];
  const float* b1 = (const float*)d_in[14];
  const float* W2 = (const float*)d_in[15];
  const float* b2 = (const float*)d_in[16];
  float* out = (float*)d_out;
  (void)in_sizes; (void)n_in; (void)out_size; (void)ws_size;

  char* ws = (char*)d_ws;
  const size_t MB = 1024 * 1024;
  const size_t KB = 1024;
  u16* wqkvT = (u16*)(ws + 0);                    // [2560x1024] bf16, 5 MB
  u16* wvuB = (u16*)(ws + 5 * MB);                // 64 KB
  float* bqkv = (float*)(ws + 5 * MB + 64 * KB);  // 10 KB
  u16* w1T = (u16*)(ws + 5 * MB + 384 * KB);      // 8 MB -> 13.375
  u16* w2T = (u16*)(ws + 13 * MB + 384 * KB);     // 8 MB -> 21.375
  u16* hbuf = (u16*)(ws + 21 * MB + 384 * KB);    // 8 MB -> 29.375
  u16* cqkv = (u16*)(ws + 29 * MB + 384 * KB);    // 20 MB -> 49.375
  u16* vT = (u16*)(ws + 49 * MB + 384 * KB);      // 8 MB -> 57.375
  float* ob = (float*)(ws + 57 * MB + 384 * KB);  // 16 MB -> 73.375
  float* x2 = (float*)(ws + 73 * MB + 384 * KB);  // 16 MB -> 89.375
  // lifetime-disjoint reuses:
  u16* ubuf = cqkv;            // 32 MB (cqkv+vT+ob[0:4MB]), dead by FFN1
  u16* p1 = (u16*)(ws + 0);    // 8 MB over wqkvT+..., dead by FFN2
  u16* p2 = (u16*)hbuf;        // 8 MB, hbuf dead after FFN1
  u16* p3 = (u16*)vT;          // 8 MB, vT dead after attention

  dim3 blk(256);
  wtrans<<<dim3(2, 32, 16), blk, 0, stream>>>(Wq, wqkvT, 1024, 64, 65536L, 65536L, C2F);
  wtrans<<<dim3(2, 32, 16), blk, 0, stream>>>(Wk, wqkvT + 1024 * 1024, 1024, 64,
                                              65536L, 65536L, 1.0f);
  wtrans<<<dim3(1, 32, 16), blk, 0, stream>>>(Wvd, wqkvT + 2048 * 1024, 1024, 32,
                                              32768L, 32768L, 1.0f);
  wconv<<<dim3(32), blk, 0, stream>>>(Wvu, wvuB, H_ * R_ * HD_);
  bconcat<<<dim3(10), blk, 0, stream>>>(bq, bk, bvd, bqkv);
  wtrans<<<dim3(128, 32, 1), blk, 0, stream>>>(W1, w1T, 1024, 4096, 0L, 0L, 1.0f);
  wtrans<<<dim3(32, 128, 1), blk, 0, stream>>>(W2, w2T, 4096, 1024, 0L, 0L, 1.0f);
  ln_kernel<<<dim3(M_), blk, 0, stream>>>(x, (const float*)nullptr, ln1_g, ln1_b,
                                          hbuf, (float*)nullptr);
  // fused QKV projection (2-phase 128² — 640 blocks, 2.5/CU)
  gemm_nt<0><<<dim3(20, 32), blk, 0, stream>>>(hbuf, wqkvT, 1024, 1024, 1024, bqkv,
                                               (const float*)nullptr, (void*)cqkv,
                                               (void*)nullptr, NQKV);
  vu_kernel<<<dim3(S_ / 64, H_, B_), blk, 0, stream>>>(cqkv, wvuB, bvu, vT);
  // attention v4: grid (H, B, 8), 512 threads, 48KB dynamic LDS
  attn_kernel<<<dim3(H_, B_, 8), dim3(512), 49152, stream>>>(cqkv, vT, ob);
  ln_kernel<<<dim3(M_), blk, 0, stream>>>(x, ob, ln2_g, ln2_b, hbuf, x2);
  // FFN1: 256² deep pipeline, grid 16x16 = 1 block/CU
  gemm8<1><<<dim3(16, 16, 1), dim3(512), 131072, stream>>>(
      hbuf, w1T, 1024, 1024, 16, b1, (float*)nullptr, ubuf,
      (u16*)nullptr, (u16*)nullptr, (u16*)nullptr, 4096);
  // FFN2: 256² split-K=4, grid 4x16x4; z=0 -> f32 into out, z>0 -> bf16 partials
  gemm8<4><<<dim3(4, 16, 4), dim3(512), 131072, stream>>>(
      ubuf, w2T, 4096, 4096, 16, (const float*)nullptr, out, (u16*)nullptr,
      p1, p2, p3, 1024);
  // out += p1+p2+p3 + b2 + x2
  reduce2<<<dim3(M_ * D_ / 1024), blk, 0, stream>>>(out, p1, p2, p3, b2, x2);
}